// Round 1
// baseline (942.546 us; speedup 1.0000x reference)
//
#include <hip/hip_runtime.h>
#include <math.h>

#define Bq  8
#define Ss  512
#define Dd  1024
#define Hh  16
#define DHd 64

// ---------------------------------------------------------------------------
// Projection GEMM: C[m][n] = sum_d A[m][d] * W[n][d] + bias[n]
// A: (M=B*S=4096, K=1024) row-major; W: (N=1024, K=1024) row-major (W^T GEMM).
// Output written directly in head layout: out[((b*H+h)*S + s)*DH + dh],
//   b = m>>9, s = m&511, h = n>>6, dh = n&63.
// Tile: BM=128, BN=64, BK=16; 256 threads; 8x4 per thread.
// ---------------------------------------------------------------------------
__global__ __launch_bounds__(256) void proj_kernel(const float* __restrict__ A,
                                                   const float* __restrict__ W,
                                                   const float* __restrict__ bias,
                                                   float* __restrict__ out)
{
    __shared__ float As[16][136];  // [k][m], pad 136 -> 16B-aligned rows
    __shared__ float Bs[16][72];   // [k][n]
    const int bm = blockIdx.y * 128;
    const int bn = blockIdx.x * 64;
    const int t  = threadIdx.x;
    const int tx = t & 15, ty = t >> 4;
    float acc[8][4] = {};

    for (int k0 = 0; k0 < Dd; k0 += 16) {
        __syncthreads();
        {
            const int c = t & 15, r = t >> 4;  // c: k-within-tile, r: row group
            #pragma unroll
            for (int i = 0; i < 8; i++)
                As[c][r + 16*i] = A[(size_t)(bm + r + 16*i)*Dd + k0 + c];
            #pragma unroll
            for (int i = 0; i < 4; i++)
                Bs[c][r + 16*i] = W[(size_t)(bn + r + 16*i)*Dd + k0 + c];
        }
        __syncthreads();
        #pragma unroll
        for (int kk = 0; kk < 16; kk++) {
            float a[8], bb[4];
            #pragma unroll
            for (int i = 0; i < 8; i++) a[i] = As[kk][ty*8 + i];
            #pragma unroll
            for (int j = 0; j < 4; j++) bb[j] = Bs[kk][tx*4 + j];
            #pragma unroll
            for (int i = 0; i < 8; i++)
                #pragma unroll
                for (int j = 0; j < 4; j++) acc[i][j] += a[i] * bb[j];
        }
    }

    #pragma unroll
    for (int i = 0; i < 8; i++) {
        const int m = bm + ty*8 + i;
        const int b = m >> 9, s = m & 511;
        #pragma unroll
        for (int j = 0; j < 4; j++) {
            const int n = bn + tx*4 + j;
            const int h = n >> 6, dh = n & 63;
            out[(((size_t)(b*Hh + h))*Ss + s)*DHd + dh] = acc[i][j] + bias[n];
        }
    }
}

// ---------------------------------------------------------------------------
// Fused attention: one block = one (b,h) x 16 q-rows.
// NOTE: R1 (sigmoid(gf-cf)+gf) is constant along the softmax axis (k) ->
// cancels in softmax; time_attn/rel_attn are head-independent; mask is causal
// triu(k=1) computed in-kernel. prob_final = c_p*softmax(scores) + c_t*time
// + c_r*rel with c_p=(1-l1)(1-l2), c_t=(1-l1)l2, c_r=l1.
// ---------------------------------------------------------------------------
__global__ __launch_bounds__(256) void attn_kernel(
    const float* __restrict__ qw, const float* __restrict__ kw,
    const float* __restrict__ vw, const float* __restrict__ rel,
    const float* __restrict__ tsp,
    const float* __restrict__ pl1, const float* __restrict__ pl2,
    float* __restrict__ out, float* __restrict__ prob)
{
    __shared__ float qs[16][64];    // Q tile
    __shared__ float kvt[64][65];   // K/V chunk, transposed: [d][k_local]
    __shared__ float sc[16][516];   // scores -> final probs

    const int t  = threadIdx.x;
    const int bh = blockIdx.y;            // b*H + h
    const int b  = bh >> 4, h = bh & 15;
    const int q0 = blockIdx.x * 16;
    const float l1 = *pl1, l2 = *pl2;
    const float c_p = (1.f - l1) * (1.f - l2);
    const float c_t = (1.f - l1) * l2;
    const float c_r = l1;
    const float* qp = qw + (size_t)bh * (Ss * DHd);
    const float* kp = kw + (size_t)bh * (Ss * DHd);
    const float* vp = vw + (size_t)bh * (Ss * DHd);

    // load Q tile (16 x 64)
    for (int i = t; i < 16*64; i += 256)
        qs[i >> 6][i & 63] = qp[(size_t)(q0 + (i >> 6)) * DHd + (i & 63)];

    // ---- scores: sc[q][k] = (q . k)/8 ----
    {
        const int kl = t & 63, qi = t >> 6;
        for (int kc = 0; kc < Ss; kc += 64) {
            __syncthreads();
            for (int i = t; i < 64*64; i += 256)           // transposed store
                kvt[i & 63][i >> 6] = kp[(size_t)(kc + (i >> 6)) * DHd + (i & 63)];
            __syncthreads();
            #pragma unroll
            for (int i = 0; i < 4; i++) {
                const int q = qi + 4*i;
                float s = 0.f;
                #pragma unroll
                for (int d = 0; d < 64; d++) s += qs[q][d] * kvt[d][kl];
                sc[q][kc + kl] = s * 0.125f;
            }
        }
    }
    __syncthreads();

    // ---- per-row softmaxes + combine; 16 threads per row ----
    {
        const int row = t >> 4, sl = t & 15;
        const int qg  = q0 + row;
        const float* tsr = tsp + ((size_t)b * Ss + qg) * Ss;
        const float* rlr = rel + ((size_t)b * Ss + qg) * Ss;

        // prob softmax (causal: k <= qg)
        float mx = -1e30f;
        #pragma unroll
        for (int j = 0; j < 32; j++) {
            const int k = sl + 16*j;
            if (k <= qg) mx = fmaxf(mx, sc[row][k]);
        }
        #pragma unroll
        for (int m = 8; m >= 1; m >>= 1) mx = fmaxf(mx, __shfl_xor(mx, m, 16));
        float sm = 0.f;
        #pragma unroll
        for (int j = 0; j < 32; j++) {
            const int k = sl + 16*j;
            if (k <= qg) sm += __expf(sc[row][k] - mx);
        }
        #pragma unroll
        for (int m = 8; m >= 1; m >>= 1) sm += __shfl_xor(sm, m, 16);
        const float pinv = 1.f / sm;

        // time softmax: values exp(-|ts|) in (0,1] -> max-sub unnecessary
        float st = 0.f;
        #pragma unroll
        for (int j = 0; j < 32; j++) {
            const int k = sl + 16*j;
            if (k <= qg) st += __expf(__expf(-fabsf(tsr[k])));
        }
        #pragma unroll
        for (int m = 8; m >= 1; m >>= 1) st += __shfl_xor(st, m, 16);
        const float tinv = 1.f / st;

        // rel softmax over ALL k (no mask): values {-10000,1,2}; exp(-10000)=0
        float sr = 0.f;
        #pragma unroll
        for (int j = 0; j < 32; j++) {
            const float rv0 = rlr[sl + 16*j];
            if (rv0 != 0.f) sr += __expf(rv0);
        }
        #pragma unroll
        for (int m = 8; m >= 1; m >>= 1) sr += __shfl_xor(sr, m, 16);
        const float rinv = (sr > 0.f) ? 1.f / sr : 0.f;
        const float runi = (sr > 0.f) ? 0.f : (1.f / (float)Ss);

        float* pr = prob + (((size_t)bh) * Ss + qg) * Ss;
        #pragma unroll
        for (int j = 0; j < 32; j++) {
            const int k = sl + 16*j;
            float p = 0.f, tv = 0.f;
            if (k <= qg) {
                p  = __expf(sc[row][k] - mx) * pinv;
                tv = __expf(__expf(-fabsf(tsr[k]))) * tinv;
            }
            const float rv0 = rlr[k];
            const float rv  = (rv0 != 0.f) ? __expf(rv0) * rinv : runi;
            const float fin = c_p * p + c_t * tv + c_r * rv;
            sc[row][k] = fin;
            pr[k] = fin;
        }
    }
    __syncthreads();

    // ---- PV: out[q][dh] = sum_k fin[q][k] * V[k][dh] ----
    {
        const int dh = t & 63, qi = t >> 6;
        float acc[4] = {0.f, 0.f, 0.f, 0.f};
        for (int kc = 0; kc < Ss; kc += 64) {
            __syncthreads();
            for (int i = t; i < 64*64; i += 256)
                kvt[i & 63][i >> 6] = vp[(size_t)(kc + (i >> 6)) * DHd + (i & 63)];
            __syncthreads();
            #pragma unroll
            for (int kk = 0; kk < 64; kk++) {
                const float vv = kvt[dh][kk];
                #pragma unroll
                for (int i = 0; i < 4; i++) acc[i] += sc[qi + 4*i][kc + kk] * vv;
            }
        }
        #pragma unroll
        for (int i = 0; i < 4; i++)
            out[((size_t)(b*Ss + q0 + qi + 4*i)) * Dd + h*DHd + dh] = acc[i];
    }
}

// ---------------------------------------------------------------------------
extern "C" void kernel_launch(void* const* d_in, const int* in_sizes, int n_in,
                              void* d_out, int out_size, void* d_ws, size_t ws_size,
                              hipStream_t stream)
{
    const float* query = (const float*)d_in[0];
    const float* key   = (const float*)d_in[1];
    const float* value = (const float*)d_in[2];
    const float* rel   = (const float*)d_in[3];
    const float* tsp   = (const float*)d_in[4];
    const float* l1    = (const float*)d_in[5];
    const float* l2    = (const float*)d_in[6];
    // d_in[7]=mask (recomputed causally), d_in[8]=encode_pos (unused)
    const float* Wq = (const float*)d_in[9];
    const float* bq = (const float*)d_in[10];
    const float* Wk = (const float*)d_in[11];
    const float* bk = (const float*)d_in[12];
    const float* Wv = (const float*)d_in[13];
    const float* bv = (const float*)d_in[14];
    // Wc/bc/Wg/bg (15..18) cancel in softmax -> unused

    float* out  = (float*)d_out;
    float* prob = (float*)d_out + (size_t)Bq * Ss * Dd;

    const size_t headN = (size_t)Bq * Hh * Ss * DHd;  // 4M floats
    float* qw = (float*)d_ws;
    float* kw = qw + headN;
    float* vw = kw + headN;   // total 48 MB of d_ws

    dim3 gp(Dd / 64, (Bq * Ss) / 128);
    proj_kernel<<<gp, 256, 0, stream>>>(query, Wq, bq, qw);
    proj_kernel<<<gp, 256, 0, stream>>>(key,   Wk, bk, kw);
    proj_kernel<<<gp, 256, 0, stream>>>(value, Wv, bv, vw);

    dim3 ga(Ss / 16, Bq * Hh);
    attn_kernel<<<ga, 256, 0, stream>>>(qw, kw, vw, rel, tsp, l1, l2, out, prob);
}

// Round 2
// 315.482 us; speedup vs baseline: 2.9876x; 2.9876x over previous
//
#include <hip/hip_runtime.h>
#include <math.h>

typedef __attribute__((ext_vector_type(8))) short short8;
typedef __attribute__((ext_vector_type(4))) float f32x4;

#define B_  8
#define S_  512
#define D_  1024
#define H_  16
#define DH_ 64

__device__ __forceinline__ unsigned short f2bf(float f) {
    unsigned int u = __float_as_uint(f);
    u += 0x7FFFu + ((u >> 16) & 1u);      // round-to-nearest-even
    return (unsigned short)(u >> 16);
}

// ---------------------------------------------------------------------------
// Projection GEMM (bf16 MFMA): C[m][n] = sum_k A[m][k] * W[n][k] + bias[n],
// then * scale, written as bf16 in head layout out[((b*H+h)*S+s)*DH+dh].
// BM=64, BN=64 (= one head), BK=64. 256 threads = 4 waves; wave w owns rows
// 16w..16w+15, all 64 cols (4 col-groups of 16).
// ---------------------------------------------------------------------------
__global__ __launch_bounds__(256, 4) void proj_mfma(
    const float* __restrict__ A, const float* __restrict__ W,
    const float* __restrict__ bias, unsigned short* __restrict__ outp,
    float scale)
{
    __shared__ unsigned short As[64][72];   // row stride 144B: 16B-aligned, 2-way-free banks
    __shared__ unsigned short Bs[64][72];
    const int t  = threadIdx.x;
    const int w  = t >> 6, l = t & 63;
    const int lr = l & 15, lg = l >> 4;
    const int bm = blockIdx.y * 64;
    const int h  = blockIdx.x;              // n-block == head

    f32x4 acc[4] = {};
    const int rs = t >> 4;                  // staging row group
    const int c4 = (t & 15) << 2;           // staging col start

    for (int k0 = 0; k0 < D_; k0 += 64) {
        __syncthreads();
        #pragma unroll
        for (int i = 0; i < 4; i++) {
            const int r = rs + 16*i;
            const float4 fa = *(const float4*)&A[(size_t)(bm + r)*D_ + k0 + c4];
            const float4 fb = *(const float4*)&W[(size_t)(h*64 + r)*D_ + k0 + c4];
            ushort4 ua; ua.x = f2bf(fa.x); ua.y = f2bf(fa.y); ua.z = f2bf(fa.z); ua.w = f2bf(fa.w);
            ushort4 ub; ub.x = f2bf(fb.x); ub.y = f2bf(fb.y); ub.z = f2bf(fb.z); ub.w = f2bf(fb.w);
            *(ushort4*)&As[r][c4] = ua;
            *(ushort4*)&Bs[r][c4] = ub;
        }
        __syncthreads();
        #pragma unroll
        for (int s = 0; s < 2; s++) {
            const short8 a = *(const short8*)&As[16*w + lr][32*s + 8*lg];
            #pragma unroll
            for (int g = 0; g < 4; g++) {
                const short8 b = *(const short8*)&Bs[16*g + lr][32*s + 8*lg];
                acc[g] = __builtin_amdgcn_mfma_f32_16x16x32_bf16(a, b, acc[g], 0, 0, 0);
            }
        }
    }

    #pragma unroll
    for (int g = 0; g < 4; g++) {
        const int dh = 16*g + lr;
        const float bv = bias[h*64 + dh];
        #pragma unroll
        for (int r = 0; r < 4; r++) {
            const int m  = bm + 16*w + 4*lg + r;        // D row = 4*(l>>4)+reg
            const int bb = m >> 9, s = m & 511;
            outp[(((size_t)(bb*H_ + h))*S_ + s)*DH_ + dh] = f2bf((acc[g][r] + bv) * scale);
        }
    }
}

// ---------------------------------------------------------------------------
// E[b][q][k] = c_t * time_attn + c_r * rel_attn  (head-independent, computed
// once). R1 is constant along k -> cancels in softmax. One wave per (b,q) row.
// ---------------------------------------------------------------------------
__global__ __launch_bounds__(256) void e_kernel(
    const float* __restrict__ rel, const float* __restrict__ tsp,
    const float* __restrict__ pl1, const float* __restrict__ pl2,
    float* __restrict__ E)
{
    const int t = threadIdx.x, w = t >> 6, l = t & 63;
    const int ridx = blockIdx.x * 4 + w;        // b*S + q
    const int q = ridx & (S_ - 1);
    const float l1 = *pl1, l2 = *pl2;
    const float c_t = (1.f - l1) * l2, c_r = l1;
    const float* tr = tsp + (size_t)ridx * S_;
    const float* rr = rel + (size_t)ridx * S_;

    float tv[8], rv[8]; float st = 0.f, sr = 0.f;
    #pragma unroll
    for (int j = 0; j < 8; j++) {
        const int k = l + 64*j;
        const float rvv = rr[k];
        rv[j] = (rvv != 0.f) ? __expf(rvv) : 0.f;   // exp(-10000)==0
        sr += rv[j];
        float tvv = 0.f;
        if (k <= q) tvv = __expf(__expf(-fabsf(tr[k])));
        tv[j] = tvv; st += tvv;
    }
    #pragma unroll
    for (int m = 32; m; m >>= 1) { st += __shfl_xor(st, m); sr += __shfl_xor(sr, m); }
    const float ti   = c_t / st;
    const float riv  = (sr > 0.f) ? c_r / sr : 0.f;
    const float runi = (sr > 0.f) ? 0.f : c_r / (float)S_;

    float* Er = E + (size_t)ridx * S_;
    #pragma unroll
    for (int j = 0; j < 8; j++) {
        const int k = l + 64*j;
        Er[k] = tv[j]*ti + rv[j]*riv + runi;
    }
}

// ---------------------------------------------------------------------------
// Fused attention, bf16 MFMA. Block = (b,h) x 64 q-rows; 4 waves, wave w owns
// q rows 16w..16w+15. Scores kept in registers (8 chunk x 4 colgroup f32x4);
// in-register softmax via shfl_xor over the 16-lane col group.
// fin = c_p * softmax(scores) + E[b,q,k]; written to prob (f32) and to LDS
// (bf16) for the PV MFMA.
// ---------------------------------------------------------------------------
__global__ __launch_bounds__(256, 2) void attn_mfma(
    const unsigned short* __restrict__ qw, const unsigned short* __restrict__ kw,
    const unsigned short* __restrict__ vw, const float* __restrict__ E,
    const float* __restrict__ pl1, const float* __restrict__ pl2,
    float* __restrict__ out, float* __restrict__ prob)
{
    __shared__ __align__(16) unsigned char smem[74752];
    unsigned short (*Qs)[72]  = (unsigned short(*)[72])smem;            // phase 1
    unsigned short (*Ks)[72]  = (unsigned short(*)[72])(smem + 9216);   // phase 1
    unsigned short (*Ps)[520] = (unsigned short(*)[520])smem;           // phase 2 (overlaps Qs/Ks)
    unsigned short *Vt        = (unsigned short*)(smem + 66560);        // [16][64][4] ushort

    const int t = threadIdx.x, w = t >> 6, l = t & 63;
    const int lr = l & 15, lg = l >> 4;
    const int bh = blockIdx.y, b = bh >> 4, h = bh & 15;
    const int q0 = blockIdx.x * 64;
    const float l1 = *pl1, l2 = *pl2;
    const float c_p = (1.f - l1) * (1.f - l2);
    const unsigned short* qp = qw + (size_t)bh * (S_ * DH_);
    const unsigned short* kp = kw + (size_t)bh * (S_ * DH_);
    const unsigned short* vp = vw + (size_t)bh * (S_ * DH_);

    // ---- stage Q (64x64 bf16) ----
    {
        const int r = t >> 4, c4 = (t & 15) << 2;
        #pragma unroll
        for (int i = 0; i < 4; i++)
            *(ushort4*)&Qs[r + 16*i][c4] = *(const ushort4*)&qp[(size_t)(q0 + r + 16*i)*DH_ + c4];
    }
    __syncthreads();
    short8 qa[2];
    qa[0] = *(const short8*)&Qs[16*w + lr][8*lg];        // A-frag: row=l&15, k contiguous
    qa[1] = *(const short8*)&Qs[16*w + lr][32 + 8*lg];

    // ---- phase 1: scores = (Q/8) . K over d=64, all 512 k in registers ----
    f32x4 sc[8][4] = {};
    for (int ch = 0; ch < 8; ch++) {
        __syncthreads();
        {
            const int r = t >> 4, c4 = (t & 15) << 2;
            #pragma unroll
            for (int i = 0; i < 4; i++)
                *(ushort4*)&Ks[r + 16*i][c4] = *(const ushort4*)&kp[(size_t)(ch*64 + r + 16*i)*DH_ + c4];
        }
        __syncthreads();
        #pragma unroll
        for (int s = 0; s < 2; s++) {
            #pragma unroll
            for (int g = 0; g < 4; g++) {
                const short8 kb = *(const short8*)&Ks[16*g + lr][32*s + 8*lg];
                sc[ch][g] = __builtin_amdgcn_mfma_f32_16x16x32_bf16(qa[s], kb, sc[ch][g], 0, 0, 0);
            }
        }
    }

    // ---- in-register causal softmax (rows 4*lg+0..3 of this wave's 16) ----
    const int qrb = q0 + 16*w + 4*lg;    // + i = absolute q row
    float mx[4] = {-1e30f, -1e30f, -1e30f, -1e30f};
    #pragma unroll
    for (int ch = 0; ch < 8; ch++)
        #pragma unroll
        for (int g = 0; g < 4; g++) {
            const int k = 64*ch + 16*g + lr;
            #pragma unroll
            for (int i = 0; i < 4; i++)
                if (k <= qrb + i) mx[i] = fmaxf(mx[i], sc[ch][g][i]);
        }
    #pragma unroll
    for (int i = 0; i < 4; i++)
        #pragma unroll
        for (int m = 8; m; m >>= 1) mx[i] = fmaxf(mx[i], __shfl_xor(mx[i], m));

    float sm[4] = {0.f, 0.f, 0.f, 0.f};
    #pragma unroll
    for (int ch = 0; ch < 8; ch++)
        #pragma unroll
        for (int g = 0; g < 4; g++) {
            const int k = 64*ch + 16*g + lr;
            #pragma unroll
            for (int i = 0; i < 4; i++) {
                if (k <= qrb + i) {
                    const float e = __expf(sc[ch][g][i] - mx[i]);
                    sc[ch][g][i] = e; sm[i] += e;
                } else sc[ch][g][i] = 0.f;
            }
        }
    #pragma unroll
    for (int i = 0; i < 4; i++)
        #pragma unroll
        for (int m = 8; m; m >>= 1) sm[i] += __shfl_xor(sm[i], m);
    float pinv[4];
    #pragma unroll
    for (int i = 0; i < 4; i++) pinv[i] = c_p / sm[i];

    __syncthreads();   // all waves done reading Qs/Ks -> safe to overwrite with Ps

    // ---- fin = c_p*p + E; write prob (f32) + Ps (bf16) ----
    {
        const float* Erow = E + (size_t)b * (S_ * S_);
        float* pr = prob + (size_t)bh * (S_ * S_);
        #pragma unroll
        for (int ch = 0; ch < 8; ch++)
            #pragma unroll
            for (int g = 0; g < 4; g++) {
                const int k = 64*ch + 16*g + lr;
                #pragma unroll
                for (int i = 0; i < 4; i++) {
                    const int qr = qrb + i;
                    const float fin = sc[ch][g][i] * pinv[i] + Erow[(size_t)qr*S_ + k];
                    pr[(size_t)qr*S_ + k] = fin;
                    Ps[16*w + 4*lg + i][k] = f2bf(fin);
                }
            }
    }

    // ---- phase 2: out = P . V ----
    f32x4 pv[4] = {};
    for (int ch = 0; ch < 8; ch++) {
        __syncthreads();
        {   // stage V chunk transposed: Vt[(kl>>2)*64 + dh][kl&3]
            #pragma unroll
            for (int i = 0; i < 4; i++) {
                const int flat = t + 256*i;
                const int kl = flat >> 4, dh4 = (flat & 15) << 2;
                const ushort4 u = *(const ushort4*)&vp[(size_t)(ch*64 + kl)*DH_ + dh4];
                Vt[((kl >> 2)*64 + dh4 + 0)*4 + (kl & 3)] = u.x;
                Vt[((kl >> 2)*64 + dh4 + 1)*4 + (kl & 3)] = u.y;
                Vt[((kl >> 2)*64 + dh4 + 2)*4 + (kl & 3)] = u.z;
                Vt[((kl >> 2)*64 + dh4 + 3)*4 + (kl & 3)] = u.w;
            }
        }
        __syncthreads();
        const ushort4* vt4 = (const ushort4*)Vt;
        #pragma unroll
        for (int s = 0; s < 2; s++) {
            const short8 pa = *(const short8*)&Ps[16*w + lr][64*ch + 32*s + 8*lg];
            #pragma unroll
            for (int g = 0; g < 4; g++) {
                union { ushort4 hh[2]; short8 v; } bb;
                bb.hh[0] = vt4[(8*s + 2*lg + 0)*64 + 16*g + lr];
                bb.hh[1] = vt4[(8*s + 2*lg + 1)*64 + 16*g + lr];
                pv[g] = __builtin_amdgcn_mfma_f32_16x16x32_bf16(pa, bb.v, pv[g], 0, 0, 0);
            }
        }
    }

    #pragma unroll
    for (int g = 0; g < 4; g++)
        #pragma unroll
        for (int i = 0; i < 4; i++) {
            const int qr = qrb + i;
            out[((size_t)(b*S_ + qr))*D_ + h*DH_ + 16*g + lr] = pv[g][i];
        }
}

// ---------------------------------------------------------------------------
extern "C" void kernel_launch(void* const* d_in, const int* in_sizes, int n_in,
                              void* d_out, int out_size, void* d_ws, size_t ws_size,
                              hipStream_t stream)
{
    const float* query = (const float*)d_in[0];
    const float* key   = (const float*)d_in[1];
    const float* value = (const float*)d_in[2];
    const float* rel   = (const float*)d_in[3];
    const float* tsp   = (const float*)d_in[4];
    const float* l1    = (const float*)d_in[5];
    const float* l2    = (const float*)d_in[6];
    // d_in[7]=mask (causal, recomputed), d_in[8]=encode_pos (unused)
    const float* Wq = (const float*)d_in[9];
    const float* bq = (const float*)d_in[10];
    const float* Wk = (const float*)d_in[11];
    const float* bk = (const float*)d_in[12];
    const float* Wv = (const float*)d_in[13];
    const float* bv = (const float*)d_in[14];
    // Wc/bc/Wg/bg (15..18): R1 is constant along softmax axis -> cancels

    float* out  = (float*)d_out;
    float* prob = (float*)d_out + (size_t)B_ * S_ * D_;

    const size_t headN = (size_t)B_ * H_ * S_ * DH_;  // 4.19M elements
    unsigned short* qw = (unsigned short*)d_ws;
    unsigned short* kw = qw + headN;
    unsigned short* vw = kw + headN;
    float* Ew = (float*)(vw + headN);                 // B*S*S f32 = 8.4 MB

    dim3 gp(H_, (B_ * S_) / 64);
    proj_mfma<<<gp, 256, 0, stream>>>(query, Wq, bq, qw, 0.125f);  // fold 1/sqrt(dh)
    proj_mfma<<<gp, 256, 0, stream>>>(key,   Wk, bk, kw, 1.0f);
    proj_mfma<<<gp, 256, 0, stream>>>(value, Wv, bv, vw, 1.0f);

    e_kernel<<<(B_ * S_) / 4, 256, 0, stream>>>(rel, tsp, l1, l2, Ew);

    dim3 ga(S_ / 64, B_ * H_);
    attn_mfma<<<ga, 256, 0, stream>>>(qw, kw, vw, Ew, l1, l2, out, prob);
}

// Round 3
// 226.183 us; speedup vs baseline: 4.1672x; 1.3948x over previous
//
#include <hip/hip_runtime.h>
#include <math.h>

typedef __attribute__((ext_vector_type(8))) short short8;
typedef __attribute__((ext_vector_type(4))) float f32x4;

#define B_  8
#define S_  512
#define D_  1024
#define H_  16
#define DH_ 64

__device__ __forceinline__ unsigned short f2bf(float f) {
    unsigned int u = __float_as_uint(f);
    u += 0x7FFFu + ((u >> 16) & 1u);      // round-to-nearest-even
    return (unsigned short)(u >> 16);
}
__device__ __forceinline__ float bf2f(unsigned short u) {
    return __uint_as_float(((unsigned int)u) << 16);
}

// ---------------------------------------------------------------------------
// f32 -> bf16 converter for the 6 GEMM operands (query,key,value,Wq,Wk,Wv).
// Abf = [3][4096][1024] bf16 (lives in the prob output region as scratch),
// Wbf = [3][1024][1024] bf16 (in ws).
// ---------------------------------------------------------------------------
__global__ __launch_bounds__(256) void conv_bf16(
    const float* __restrict__ q, const float* __restrict__ k, const float* __restrict__ v,
    const float* __restrict__ wq, const float* __restrict__ wk, const float* __restrict__ wv,
    unsigned short* __restrict__ Abf, unsigned short* __restrict__ Wbf)
{
    const size_t NA = 1048576;   // float4s per A tensor (4M elts / 4)
    const size_t NW = 262144;    // float4s per W tensor
    const size_t total = 3*NA + 3*NW;
    for (size_t i4 = (size_t)blockIdx.x*blockDim.x + threadIdx.x; i4 < total;
         i4 += (size_t)gridDim.x*blockDim.x) {
        const float* s; unsigned short* d; size_t off;
        if (i4 < 3*NA) {
            const int z = (int)(i4 / NA);
            s = (z == 0) ? q : (z == 1) ? k : v;
            off = i4 - (size_t)z*NA;
            d = Abf + (size_t)z*NA*4;
        } else {
            const size_t j = i4 - 3*NA;
            const int z = (int)(j / NW);
            s = (z == 0) ? wq : (z == 1) ? wk : wv;
            off = j - (size_t)z*NW;
            d = Wbf + (size_t)z*NW*4;
        }
        const float4 f = ((const float4*)s)[off];
        ushort4 u; u.x = f2bf(f.x); u.y = f2bf(f.y); u.z = f2bf(f.z); u.w = f2bf(f.w);
        ((ushort4*)d)[off] = u;
    }
}

// ---------------------------------------------------------------------------
// QKV projection GEMM, LDS-free: 128x128 tile, 4 waves in 2x2 quadrants,
// MFMA fragments loaded directly from global (16B contiguous, L2-resident).
// C[m][n] = sum_k A[m][k]*W[n][k]; out = bf16((C+bias)*scale) in head layout.
// grid = (8 nblk, 32 mblk, 3 tensors).
// ---------------------------------------------------------------------------
__global__ __launch_bounds__(256) void qkv_gemm(
    const unsigned short* __restrict__ Abf, const unsigned short* __restrict__ Wbf,
    const float* __restrict__ bq, const float* __restrict__ bk, const float* __restrict__ bv,
    unsigned short* __restrict__ qw, unsigned short* __restrict__ kw,
    unsigned short* __restrict__ vw)
{
    const int z = blockIdx.z;
    const unsigned short* A = Abf + (size_t)z * 4194304;
    const unsigned short* W = Wbf + (size_t)z * 1048576;
    const float* bias = (z == 0) ? bq : (z == 1) ? bk : bv;
    unsigned short* outp = (z == 0) ? qw : (z == 1) ? kw : vw;
    const float scale = (z == 0) ? 0.125f : 1.0f;   // fold 1/sqrt(dh) into q

    const int bm = blockIdx.y * 128, bn = blockIdx.x * 128;
    const int t = threadIdx.x, w = t >> 6, l = t & 63, lr = l & 15, lg = l >> 4;
    const int wr = (w >> 1) * 64, wc = (w & 1) * 64;

    const unsigned short* Ab = A + (size_t)(bm + wr + lr) * 1024 + 8*lg;
    const unsigned short* Wb = W + (size_t)(bn + wc + lr) * 1024 + 8*lg;

    f32x4 acc[4][4] = {};
    for (int k0 = 0; k0 < 1024; k0 += 32) {
        short8 af[4], bf[4];
        #pragma unroll
        for (int i = 0; i < 4; i++) af[i] = *(const short8*)(Ab + (size_t)(16*i)*1024 + k0);
        #pragma unroll
        for (int j = 0; j < 4; j++) bf[j] = *(const short8*)(Wb + (size_t)(16*j)*1024 + k0);
        #pragma unroll
        for (int i = 0; i < 4; i++)
            #pragma unroll
            for (int j = 0; j < 4; j++)
                acc[i][j] = __builtin_amdgcn_mfma_f32_16x16x32_bf16(af[i], bf[j], acc[i][j], 0, 0, 0);
    }

    #pragma unroll
    for (int j = 0; j < 4; j++) {
        const int n = bn + wc + 16*j + lr;
        const float bvx = bias[n];
        const int h = n >> 6, dh = n & 63;
        #pragma unroll
        for (int i = 0; i < 4; i++)
            #pragma unroll
            for (int r = 0; r < 4; r++) {
                const int m = bm + wr + 16*i + 4*lg + r;     // D row = 4*(l>>4)+reg
                const int bb = m >> 9, s = m & 511;
                outp[(((size_t)(bb*H_ + h))*S_ + s)*DH_ + dh] = f2bf((acc[i][j][r] + bvx) * scale);
            }
    }
}

// ---------------------------------------------------------------------------
// V transpose: vtw[bh][dh][s] = vw[bh][s][dh] so PV B-fragments are 16B
// contiguous in global. grid = (8 s-chunks, 128 bh).
// ---------------------------------------------------------------------------
__global__ __launch_bounds__(256) void vtrans(const unsigned short* __restrict__ vw,
                                              unsigned short* __restrict__ vtw)
{
    __shared__ unsigned short tile[64][68];
    const int bh = blockIdx.y, sc = blockIdx.x * 64;
    const unsigned short* src = vw + (size_t)bh * S_ * DH_;
    unsigned short* dst = vtw + (size_t)bh * DH_ * S_;
    const int t = threadIdx.x;
    const int r = t >> 4, c4 = (t & 15) << 2;
    #pragma unroll
    for (int i = 0; i < 4; i++)
        *(ushort4*)&tile[r + 16*i][c4] = *(const ushort4*)&src[(size_t)(sc + r + 16*i)*DH_ + c4];
    __syncthreads();
    const int dh = t >> 2, sg = (t & 3) * 16;
    #pragma unroll
    for (int e = 0; e < 16; e += 4) {
        ushort4 u;
        u.x = tile[sg + e + 0][dh]; u.y = tile[sg + e + 1][dh];
        u.z = tile[sg + e + 2][dh]; u.w = tile[sg + e + 3][dh];
        *(ushort4*)&dst[(size_t)dh*S_ + sc + sg + e] = u;
    }
}

// ---------------------------------------------------------------------------
// E[b][q][k] = c_t*time_attn + c_r*rel_attn  (head-independent), bf16 out.
// R1 = sigmoid(gf-cf)+gf is constant along k -> cancels in softmax.
// ---------------------------------------------------------------------------
__global__ __launch_bounds__(256) void e_kernel(
    const float* __restrict__ rel, const float* __restrict__ tsp,
    const float* __restrict__ pl1, const float* __restrict__ pl2,
    unsigned short* __restrict__ E)
{
    const int t = threadIdx.x, w = t >> 6, l = t & 63;
    const int ridx = blockIdx.x * 4 + w;        // b*S + q
    const int q = ridx & (S_ - 1);
    const float l1 = *pl1, l2 = *pl2;
    const float c_t = (1.f - l1) * l2, c_r = l1;
    const float* tr = tsp + (size_t)ridx * S_;
    const float* rr = rel + (size_t)ridx * S_;

    float tv[8], rv[8]; float st = 0.f, sr = 0.f;
    #pragma unroll
    for (int j = 0; j < 8; j++) {
        const int k = l + 64*j;
        const float rvv = rr[k];
        rv[j] = (rvv != 0.f) ? __expf(rvv) : 0.f;   // exp(-10000)==0 exactly
        sr += rv[j];
        float tvv = 0.f;
        if (k <= q) tvv = __expf(__expf(-fabsf(tr[k])));
        tv[j] = tvv; st += tvv;
    }
    #pragma unroll
    for (int m = 32; m; m >>= 1) { st += __shfl_xor(st, m); sr += __shfl_xor(sr, m); }
    const float ti   = c_t / st;
    const float riv  = (sr > 0.f) ? c_r / sr : 0.f;
    const float runi = (sr > 0.f) ? 0.f : c_r / (float)S_;

    unsigned short* Er = E + (size_t)ridx * S_;
    #pragma unroll
    for (int j = 0; j < 8; j++) {
        const int k = l + 64*j;
        Er[k] = f2bf(tv[j]*ti + rv[j]*riv + runi);
    }
}

// ---------------------------------------------------------------------------
// Fused attention. Block = (b,h) x 64 q-rows; 4 waves, wave w owns q rows
// 16w..16w+15. Pass 1: QK^T with direct-global K fragments, scores packed to
// bf16 pairs in registers (causal mask at pack). In-register softmax.
// Pass 2 per 64-col chunk: fin = p*pinv + E -> Ps (LDS, bf16); PV MFMA with
// direct-global V^T fragments; vectorized prob writes from Ps.
// ---------------------------------------------------------------------------
__global__ __launch_bounds__(256) void attn_mfma(
    const unsigned short* __restrict__ qw, const unsigned short* __restrict__ kw,
    const unsigned short* __restrict__ vtw, const unsigned short* __restrict__ E,
    const float* __restrict__ pl1, const float* __restrict__ pl2,
    float* __restrict__ out, float* __restrict__ prob)
{
    __shared__ unsigned short Ps[64][72];

    const int t = threadIdx.x, w = t >> 6, l = t & 63, lr = l & 15, lg = l >> 4;
    const int bh = blockIdx.y, b = bh >> 4, h = bh & 15;
    const int q0 = blockIdx.x * 64;
    const float l1 = *pl1, l2 = *pl2;
    const float c_p = (1.f - l1) * (1.f - l2);
    const unsigned short* qp = qw + (size_t)bh * (S_ * DH_);
    const unsigned short* kp = kw + (size_t)bh * (S_ * DH_);
    const unsigned short* vt = vtw + (size_t)bh * (DH_ * S_);

    short8 qa[2];
    #pragma unroll
    for (int s = 0; s < 2; s++)
        qa[s] = *(const short8*)&qp[(size_t)(q0 + 16*w + lr)*DH_ + 32*s + 8*lg];

    const int qrb = q0 + 16*w + 4*lg;    // +i = absolute q row for acc elem i

    // ---- pass 1: QK^T, pack scores (bf16 pairs) with causal mask ----
    unsigned int scp[8][4][2];
    #pragma unroll
    for (int ch = 0; ch < 8; ch++) {
        f32x4 a4[4] = {};
        #pragma unroll
        for (int s = 0; s < 2; s++)
            #pragma unroll
            for (int g = 0; g < 4; g++) {
                const short8 kb = *(const short8*)&kp[(size_t)(ch*64 + 16*g + lr)*DH_ + 32*s + 8*lg];
                a4[g] = __builtin_amdgcn_mfma_f32_16x16x32_bf16(qa[s], kb, a4[g], 0, 0, 0);
            }
        #pragma unroll
        for (int g = 0; g < 4; g++) {
            const int k = 64*ch + 16*g + lr;
            const float v0 = (k <= qrb + 0) ? a4[g][0] : -1e30f;
            const float v1 = (k <= qrb + 1) ? a4[g][1] : -1e30f;
            const float v2 = (k <= qrb + 2) ? a4[g][2] : -1e30f;
            const float v3 = (k <= qrb + 3) ? a4[g][3] : -1e30f;
            scp[ch][g][0] = ((unsigned)f2bf(v1) << 16) | f2bf(v0);
            scp[ch][g][1] = ((unsigned)f2bf(v3) << 16) | f2bf(v2);
        }
    }

    // ---- softmax over packed scores ----
    float mx[4] = {-1e30f, -1e30f, -1e30f, -1e30f};
    #pragma unroll
    for (int ch = 0; ch < 8; ch++)
        #pragma unroll
        for (int g = 0; g < 4; g++) {
            const unsigned u0 = scp[ch][g][0], u1 = scp[ch][g][1];
            mx[0] = fmaxf(mx[0], __uint_as_float(u0 << 16));
            mx[1] = fmaxf(mx[1], __uint_as_float(u0 & 0xffff0000u));
            mx[2] = fmaxf(mx[2], __uint_as_float(u1 << 16));
            mx[3] = fmaxf(mx[3], __uint_as_float(u1 & 0xffff0000u));
        }
    #pragma unroll
    for (int i = 0; i < 4; i++)
        #pragma unroll
        for (int m = 8; m; m >>= 1) mx[i] = fmaxf(mx[i], __shfl_xor(mx[i], m));

    float sm[4] = {0.f, 0.f, 0.f, 0.f};
    #pragma unroll
    for (int ch = 0; ch < 8; ch++)
        #pragma unroll
        for (int g = 0; g < 4; g++) {
            const unsigned u0 = scp[ch][g][0], u1 = scp[ch][g][1];
            const float e0 = __expf(__uint_as_float(u0 << 16)          - mx[0]);
            const float e1 = __expf(__uint_as_float(u0 & 0xffff0000u) - mx[1]);
            const float e2 = __expf(__uint_as_float(u1 << 16)          - mx[2]);
            const float e3 = __expf(__uint_as_float(u1 & 0xffff0000u) - mx[3]);
            sm[0] += e0; sm[1] += e1; sm[2] += e2; sm[3] += e3;
            scp[ch][g][0] = ((unsigned)f2bf(e1) << 16) | f2bf(e0);
            scp[ch][g][1] = ((unsigned)f2bf(e3) << 16) | f2bf(e2);
        }
    #pragma unroll
    for (int i = 0; i < 4; i++)
        #pragma unroll
        for (int m = 8; m; m >>= 1) sm[i] += __shfl_xor(sm[i], m);
    float pinv[4];
    #pragma unroll
    for (int i = 0; i < 4; i++) pinv[i] = c_p / sm[i];

    // ---- pass 2: fin -> Ps; PV MFMA; prob writes ----
    f32x4 pv[4] = {};
    const unsigned short* Eb = E + ((size_t)b * S_ + qrb) * S_;
    float* pr = prob + (size_t)bh * (S_ * S_);
    const int prow = 16*w + 4*lg;

    #pragma unroll
    for (int ch = 0; ch < 8; ch++) {
        __syncthreads();   // previous chunk's Ps fully consumed
        #pragma unroll
        for (int g = 0; g < 4; g++) {
            const int kc = 16*g + lr;
            const unsigned u0 = scp[ch][g][0], u1 = scp[ch][g][1];
            const size_t eb = (size_t)(64*ch + kc);
            Ps[prow + 0][kc] = f2bf(__uint_as_float(u0 << 16)          * pinv[0] + bf2f(Eb[eb]));
            Ps[prow + 1][kc] = f2bf(__uint_as_float(u0 & 0xffff0000u) * pinv[1] + bf2f(Eb[eb + 512]));
            Ps[prow + 2][kc] = f2bf(__uint_as_float(u1 << 16)          * pinv[2] + bf2f(Eb[eb + 1024]));
            Ps[prow + 3][kc] = f2bf(__uint_as_float(u1 & 0xffff0000u) * pinv[3] + bf2f(Eb[eb + 1536]));
        }
        __syncthreads();
        #pragma unroll
        for (int s = 0; s < 2; s++) {
            const short8 pa = *(const short8*)&Ps[16*w + lr][32*s + 8*lg];
            #pragma unroll
            for (int g = 0; g < 4; g++) {
                const short8 vb = *(const short8*)&vt[(size_t)(16*g + lr)*S_ + 64*ch + 32*s + 8*lg];
                pv[g] = __builtin_amdgcn_mfma_f32_16x16x32_bf16(pa, vb, pv[g], 0, 0, 0);
            }
        }
        {   // vectorized prob writes from Ps (bf16 -> f32)
            const int rr = t >> 2, sg = (t & 3) * 16;
            float* prr = &pr[(size_t)(q0 + rr)*S_ + 64*ch + sg];
            #pragma unroll
            for (int jj = 0; jj < 2; jj++) {
                const short8 u = *(const short8*)&Ps[rr][sg + 8*jj];
                float4 f0, f1;
                f0.x = bf2f((unsigned short)u[0]); f0.y = bf2f((unsigned short)u[1]);
                f0.z = bf2f((unsigned short)u[2]); f0.w = bf2f((unsigned short)u[3]);
                f1.x = bf2f((unsigned short)u[4]); f1.y = bf2f((unsigned short)u[5]);
                f1.z = bf2f((unsigned short)u[6]); f1.w = bf2f((unsigned short)u[7]);
                *(float4*)&prr[8*jj]     = f0;
                *(float4*)&prr[8*jj + 4] = f1;
            }
        }
    }

    #pragma unroll
    for (int g = 0; g < 4; g++)
        #pragma unroll
        for (int i = 0; i < 4; i++)
            out[((size_t)(b*S_ + qrb + i))*D_ + h*DH_ + 16*g + lr] = pv[g][i];
}

// ---------------------------------------------------------------------------
extern "C" void kernel_launch(void* const* d_in, const int* in_sizes, int n_in,
                              void* d_out, int out_size, void* d_ws, size_t ws_size,
                              hipStream_t stream)
{
    const float* query = (const float*)d_in[0];
    const float* key   = (const float*)d_in[1];
    const float* value = (const float*)d_in[2];
    const float* rel   = (const float*)d_in[3];
    const float* tsp   = (const float*)d_in[4];
    const float* l1    = (const float*)d_in[5];
    const float* l2    = (const float*)d_in[6];
    // d_in[7]=mask (causal, recomputed), d_in[8]=encode_pos (unused)
    const float* Wq = (const float*)d_in[9];
    const float* bq = (const float*)d_in[10];
    const float* Wk = (const float*)d_in[11];
    const float* bk = (const float*)d_in[12];
    const float* Wv = (const float*)d_in[13];
    const float* bv = (const float*)d_in[14];
    // Wc/bc/Wg/bg (15..18): R1 constant along softmax axis -> cancels

    float* out  = (float*)d_out;
    float* prob = (float*)d_out + (size_t)B_ * S_ * D_;

    // Abf scratch lives in the prob region (written before attn overwrites it)
    unsigned short* Abf = (unsigned short*)prob;           // 3*4M bf16 = 25 MB

    const size_t headN = (size_t)B_ * H_ * S_ * DH_;       // 4,194,304
    unsigned short* Wbf = (unsigned short*)d_ws;           // 3*1M
    unsigned short* qw  = Wbf + 3*1048576;
    unsigned short* kw  = qw + headN;
    unsigned short* vw  = kw + headN;
    unsigned short* vtw = vw + headN;
    unsigned short* Ew  = vtw + headN;                     // B*S*S bf16 = 4.2 MB

    conv_bf16<<<2048, 256, 0, stream>>>(query, key, value, Wq, Wk, Wv, Abf, Wbf);

    dim3 gg(8, 32, 3);
    qkv_gemm<<<gg, 256, 0, stream>>>(Abf, Wbf, bq, bk, bv, qw, kw, vw);

    dim3 gt(8, B_ * H_);
    vtrans<<<gt, 256, 0, stream>>>(vw, vtw);

    e_kernel<<<(B_ * S_) / 4, 256, 0, stream>>>(rel, tsp, l1, l2, Ew);

    dim3 ga(S_ / 64, B_ * H_);
    attn_mfma<<<ga, 256, 0, stream>>>(qw, kw, vtw, Ew, l1, l2, out, prob);
}

// Round 4
// 159.939 us; speedup vs baseline: 5.8932x; 1.4142x over previous
//
#include <hip/hip_runtime.h>
#include <math.h>

typedef __attribute__((ext_vector_type(8))) short short8;
typedef __attribute__((ext_vector_type(4))) float f32x4;

#define B_  8
#define S_  512
#define D_  1024
#define H_  16
#define DH_ 64

__device__ __forceinline__ unsigned short f2bf(float f) {
    unsigned int u = __float_as_uint(f);
    u += 0x7FFFu + ((u >> 16) & 1u);      // round-to-nearest-even
    return (unsigned short)(u >> 16);
}
__device__ __forceinline__ float bf2f(unsigned short u) {
    return __uint_as_float(((unsigned int)u) << 16);
}
__device__ __forceinline__ void gload_lds16(const void* g, void* l) {
    __builtin_amdgcn_global_load_lds(
        (const __attribute__((address_space(1))) unsigned int*)g,
        (__attribute__((address_space(3))) unsigned int*)l, 16, 0, 0);
}

// ---------------------------------------------------------------------------
// f32 -> bf16 converter for the 6 GEMM operands (query,key,value,Wq,Wk,Wv).
// ---------------------------------------------------------------------------
__global__ __launch_bounds__(256) void conv_bf16(
    const float* __restrict__ q, const float* __restrict__ k, const float* __restrict__ v,
    const float* __restrict__ wq, const float* __restrict__ wk, const float* __restrict__ wv,
    unsigned short* __restrict__ Abf, unsigned short* __restrict__ Wbf)
{
    const size_t NA = 1048576;   // float4s per A tensor (4M elts / 4)
    const size_t NW = 262144;    // float4s per W tensor
    const size_t total = 3*NA + 3*NW;
    for (size_t i4 = (size_t)blockIdx.x*blockDim.x + threadIdx.x; i4 < total;
         i4 += (size_t)gridDim.x*blockDim.x) {
        const float* s; unsigned short* d; size_t off;
        if (i4 < 3*NA) {
            const int z = (int)(i4 / NA);
            s = (z == 0) ? q : (z == 1) ? k : v;
            off = i4 - (size_t)z*NA;
            d = Abf + (size_t)z*NA*4;
        } else {
            const size_t j = i4 - 3*NA;
            const int z = (int)(j / NW);
            s = (z == 0) ? wq : (z == 1) ? wk : wv;
            off = j - (size_t)z*NW;
            d = Wbf + (size_t)z*NW*4;
        }
        const float4 f = ((const float4*)s)[off];
        ushort4 u; u.x = f2bf(f.x); u.y = f2bf(f.y); u.z = f2bf(f.z); u.w = f2bf(f.w);
        ((ushort4*)d)[off] = u;
    }
}

// ---------------------------------------------------------------------------
// QKV projection GEMM, m97 structure: 128x128 tile, BK=64, 4 waves (2x2
// quadrants, 4x4 16x16 frags each), global_load_lds(16B) staging into
// XOR-swizzled LDS (linear dest + pre-swizzled source + swizzled ds_read).
// 1D grid 768 = 8(nx) * 32(my) * 3(z), XCD-bijective swizzle (768%8==0).
// ---------------------------------------------------------------------------
__global__ __launch_bounds__(256) void qkv_gemm(
    const unsigned short* __restrict__ Abf, const unsigned short* __restrict__ Wbf,
    const float* __restrict__ bq, const float* __restrict__ bk, const float* __restrict__ bv,
    unsigned short* __restrict__ qw, unsigned short* __restrict__ kw,
    unsigned short* __restrict__ vw)
{
    __shared__ unsigned short As[128][64];   // 16 KB, content XOR-swizzled
    __shared__ unsigned short Bs[128][64];

    // XCD-aware bijective remap: 768 blocks, 96 per XCD chunk
    const int bid = blockIdx.x;
    const int wid = (bid & 7) * 96 + (bid >> 3);
    const int z   = wid >> 8;            // tensor
    const int rem = wid & 255;
    const int bm  = (rem >> 3) * 128;    // m-block
    const int bn  = (rem & 7) * 128;     // n-block

    const unsigned short* A = Abf + (size_t)z * 4194304;
    const unsigned short* W = Wbf + (size_t)z * 1048576;
    const float* bias = (z == 0) ? bq : (z == 1) ? bk : bv;
    unsigned short* outp = (z == 0) ? qw : (z == 1) ? kw : vw;
    const float scale = (z == 0) ? 0.125f : 1.0f;   // fold 1/sqrt(dh) into q

    const int t = threadIdx.x, w = t >> 6, l = t & 63, lr = l & 15, lg = l >> 4;
    const int wr = (w >> 1) * 64, wc = (w & 1) * 64;

    // staging: thread t -> LDS linear offset 4096*j + t*16 (wave-uniform+lane*16)
    const int srow = t >> 3;                       // 0..31
    const int scol = 8 * ((t & 7) ^ (srow & 7));   // pre-swizzled source col
    const unsigned short* Ast = A + (size_t)(bm + srow) * 1024 + scol;
    const unsigned short* Wst = W + (size_t)(bn + srow) * 1024 + scol;
    char* AsB = (char*)As; char* BsB = (char*)Bs;

    f32x4 acc[4][4] = {};
    for (int k0 = 0; k0 < 1024; k0 += 64) {
        __syncthreads();                           // prev tile fully consumed
        #pragma unroll
        for (int j = 0; j < 4; j++) {
            gload_lds16(Ast + (size_t)(32*j)*1024 + k0, AsB + 4096*j + t*16);
            gload_lds16(Wst + (size_t)(32*j)*1024 + k0, BsB + 4096*j + t*16);
        }
        __syncthreads();                           // vmcnt(0) drained by barrier
        #pragma unroll
        for (int s = 0; s < 2; s++) {
            short8 af[4], bf4[4];
            #pragma unroll
            for (int i = 0; i < 4; i++) {
                const int row = wr + 16*i + lr;
                af[i] = *(const short8*)(AsB + row*128 + (((4*s + lg) ^ (row & 7)) << 4));
            }
            #pragma unroll
            for (int j = 0; j < 4; j++) {
                const int row = wc + 16*j + lr;
                bf4[j] = *(const short8*)(BsB + row*128 + (((4*s + lg) ^ (row & 7)) << 4));
            }
            #pragma unroll
            for (int i = 0; i < 4; i++)
                #pragma unroll
                for (int j = 0; j < 4; j++)
                    acc[i][j] = __builtin_amdgcn_mfma_f32_16x16x32_bf16(af[i], bf4[j], acc[i][j], 0, 0, 0);
        }
    }

    #pragma unroll
    for (int j = 0; j < 4; j++) {
        const int n = bn + wc + 16*j + lr;
        const float bvx = bias[n];
        const int h = n >> 6, dh = n & 63;
        #pragma unroll
        for (int i = 0; i < 4; i++)
            #pragma unroll
            for (int r = 0; r < 4; r++) {
                const int m = bm + wr + 16*i + 4*lg + r;     // D row = 4*(l>>4)+reg
                const int bb = m >> 9, s = m & 511;
                outp[(((size_t)(bb*H_ + h))*S_ + s)*DH_ + dh] = f2bf((acc[i][j][r] + bvx) * scale);
            }
    }
}

// ---------------------------------------------------------------------------
// V transpose: vtw[bh][dh][s] = vw[bh][s][dh].
// ---------------------------------------------------------------------------
__global__ __launch_bounds__(256) void vtrans(const unsigned short* __restrict__ vw,
                                              unsigned short* __restrict__ vtw)
{
    __shared__ unsigned short tile[64][68];
    const int bh = blockIdx.y, sc = blockIdx.x * 64;
    const unsigned short* src = vw + (size_t)bh * S_ * DH_;
    unsigned short* dst = vtw + (size_t)bh * DH_ * S_;
    const int t = threadIdx.x;
    const int r = t >> 4, c4 = (t & 15) << 2;
    #pragma unroll
    for (int i = 0; i < 4; i++)
        *(ushort4*)&tile[r + 16*i][c4] = *(const ushort4*)&src[(size_t)(sc + r + 16*i)*DH_ + c4];
    __syncthreads();
    const int dh = t >> 2, sg = (t & 3) * 16;
    #pragma unroll
    for (int e = 0; e < 16; e += 4) {
        ushort4 u;
        u.x = tile[sg + e + 0][dh]; u.y = tile[sg + e + 1][dh];
        u.z = tile[sg + e + 2][dh]; u.w = tile[sg + e + 3][dh];
        *(ushort4*)&dst[(size_t)dh*S_ + sc + sg + e] = u;
    }
}

// ---------------------------------------------------------------------------
// E[b][q][k] = c_t*time_attn + c_r*rel_attn  (head-independent), bf16 out.
// R1 = sigmoid(gf-cf)+gf is constant along k -> cancels in softmax.
// ---------------------------------------------------------------------------
__global__ __launch_bounds__(256) void e_kernel(
    const float* __restrict__ rel, const float* __restrict__ tsp,
    const float* __restrict__ pl1, const float* __restrict__ pl2,
    unsigned short* __restrict__ E)
{
    const int t = threadIdx.x, w = t >> 6, l = t & 63;
    const int ridx = blockIdx.x * 4 + w;        // b*S + q
    const int q = ridx & (S_ - 1);
    const float l1 = *pl1, l2 = *pl2;
    const float c_t = (1.f - l1) * l2, c_r = l1;
    const float* tr = tsp + (size_t)ridx * S_;
    const float* rr = rel + (size_t)ridx * S_;

    float tv[8], rv[8]; float st = 0.f, sr = 0.f;
    #pragma unroll
    for (int j = 0; j < 8; j++) {
        const int k = l + 64*j;
        const float rvv = rr[k];
        rv[j] = (rvv != 0.f) ? __expf(rvv) : 0.f;   // exp(-10000)==0 exactly
        sr += rv[j];
        float tvv = 0.f;
        if (k <= q) tvv = __expf(__expf(-fabsf(tr[k])));
        tv[j] = tvv; st += tvv;
    }
    #pragma unroll
    for (int m = 32; m; m >>= 1) { st += __shfl_xor(st, m); sr += __shfl_xor(sr, m); }
    const float ti   = c_t / st;
    const float riv  = (sr > 0.f) ? c_r / sr : 0.f;
    const float runi = (sr > 0.f) ? 0.f : c_r / (float)S_;

    unsigned short* Er = E + (size_t)ridx * S_;
    #pragma unroll
    for (int j = 0; j < 8; j++) {
        const int k = l + 64*j;
        Er[k] = f2bf(tv[j]*ti + rv[j]*riv + runi);
    }
}

// ---------------------------------------------------------------------------
// Fused attention (unchanged from R2). Block = (b,h) x 64 q-rows.
// ---------------------------------------------------------------------------
__global__ __launch_bounds__(256) void attn_mfma(
    const unsigned short* __restrict__ qw, const unsigned short* __restrict__ kw,
    const unsigned short* __restrict__ vtw, const unsigned short* __restrict__ E,
    const float* __restrict__ pl1, const float* __restrict__ pl2,
    float* __restrict__ out, float* __restrict__ prob)
{
    __shared__ unsigned short Ps[64][72];

    const int t = threadIdx.x, w = t >> 6, l = t & 63, lr = l & 15, lg = l >> 4;
    const int bh = blockIdx.y, b = bh >> 4, h = bh & 15;
    const int q0 = blockIdx.x * 64;
    const float l1 = *pl1, l2 = *pl2;
    const float c_p = (1.f - l1) * (1.f - l2);
    const unsigned short* qp = qw + (size_t)bh * (S_ * DH_);
    const unsigned short* kp = kw + (size_t)bh * (S_ * DH_);
    const unsigned short* vt = vtw + (size_t)bh * (DH_ * S_);

    short8 qa[2];
    #pragma unroll
    for (int s = 0; s < 2; s++)
        qa[s] = *(const short8*)&qp[(size_t)(q0 + 16*w + lr)*DH_ + 32*s + 8*lg];

    const int qrb = q0 + 16*w + 4*lg;    // +i = absolute q row for acc elem i

    // ---- pass 1: QK^T, pack scores (bf16 pairs) with causal mask ----
    unsigned int scp[8][4][2];
    #pragma unroll
    for (int ch = 0; ch < 8; ch++) {
        f32x4 a4[4] = {};
        #pragma unroll
        for (int s = 0; s < 2; s++)
            #pragma unroll
            for (int g = 0; g < 4; g++) {
                const short8 kb = *(const short8*)&kp[(size_t)(ch*64 + 16*g + lr)*DH_ + 32*s + 8*lg];
                a4[g] = __builtin_amdgcn_mfma_f32_16x16x32_bf16(qa[s], kb, a4[g], 0, 0, 0);
            }
        #pragma unroll
        for (int g = 0; g < 4; g++) {
            const int k = 64*ch + 16*g + lr;
            const float v0 = (k <= qrb + 0) ? a4[g][0] : -1e30f;
            const float v1 = (k <= qrb + 1) ? a4[g][1] : -1e30f;
            const float v2 = (k <= qrb + 2) ? a4[g][2] : -1e30f;
            const float v3 = (k <= qrb + 3) ? a4[g][3] : -1e30f;
            scp[ch][g][0] = ((unsigned)f2bf(v1) << 16) | f2bf(v0);
            scp[ch][g][1] = ((unsigned)f2bf(v3) << 16) | f2bf(v2);
        }
    }

    // ---- softmax over packed scores ----
    float mx[4] = {-1e30f, -1e30f, -1e30f, -1e30f};
    #pragma unroll
    for (int ch = 0; ch < 8; ch++)
        #pragma unroll
        for (int g = 0; g < 4; g++) {
            const unsigned u0 = scp[ch][g][0], u1 = scp[ch][g][1];
            mx[0] = fmaxf(mx[0], __uint_as_float(u0 << 16));
            mx[1] = fmaxf(mx[1], __uint_as_float(u0 & 0xffff0000u));
            mx[2] = fmaxf(mx[2], __uint_as_float(u1 << 16));
            mx[3] = fmaxf(mx[3], __uint_as_float(u1 & 0xffff0000u));
        }
    #pragma unroll
    for (int i = 0; i < 4; i++)
        #pragma unroll
        for (int m = 8; m; m >>= 1) mx[i] = fmaxf(mx[i], __shfl_xor(mx[i], m));

    float sm[4] = {0.f, 0.f, 0.f, 0.f};
    #pragma unroll
    for (int ch = 0; ch < 8; ch++)
        #pragma unroll
        for (int g = 0; g < 4; g++) {
            const unsigned u0 = scp[ch][g][0], u1 = scp[ch][g][1];
            const float e0 = __expf(__uint_as_float(u0 << 16)          - mx[0]);
            const float e1 = __expf(__uint_as_float(u0 & 0xffff0000u) - mx[1]);
            const float e2 = __expf(__uint_as_float(u1 << 16)          - mx[2]);
            const float e3 = __expf(__uint_as_float(u1 & 0xffff0000u) - mx[3]);
            sm[0] += e0; sm[1] += e1; sm[2] += e2; sm[3] += e3;
            scp[ch][g][0] = ((unsigned)f2bf(e1) << 16) | f2bf(e0);
            scp[ch][g][1] = ((unsigned)f2bf(e3) << 16) | f2bf(e2);
        }
    #pragma unroll
    for (int i = 0; i < 4; i++)
        #pragma unroll
        for (int m = 8; m; m >>= 1) sm[i] += __shfl_xor(sm[i], m);
    float pinv[4];
    #pragma unroll
    for (int i = 0; i < 4; i++) pinv[i] = c_p / sm[i];

    // ---- pass 2: fin -> Ps; PV MFMA; prob writes ----
    f32x4 pv[4] = {};
    const unsigned short* Eb = E + ((size_t)b * S_ + qrb) * S_;
    float* pr = prob + (size_t)bh * (S_ * S_);
    const int prow = 16*w + 4*lg;

    #pragma unroll
    for (int ch = 0; ch < 8; ch++) {
        __syncthreads();   // previous chunk's Ps fully consumed
        #pragma unroll
        for (int g = 0; g < 4; g++) {
            const int kc = 16*g + lr;
            const unsigned u0 = scp[ch][g][0], u1 = scp[ch][g][1];
            const size_t eb = (size_t)(64*ch + kc);
            Ps[prow + 0][kc] = f2bf(__uint_as_float(u0 << 16)          * pinv[0] + bf2f(Eb[eb]));
            Ps[prow + 1][kc] = f2bf(__uint_as_float(u0 & 0xffff0000u) * pinv[1] + bf2f(Eb[eb + 512]));
            Ps[prow + 2][kc] = f2bf(__uint_as_float(u1 << 16)          * pinv[2] + bf2f(Eb[eb + 1024]));
            Ps[prow + 3][kc] = f2bf(__uint_as_float(u1 & 0xffff0000u) * pinv[3] + bf2f(Eb[eb + 1536]));
        }
        __syncthreads();
        #pragma unroll
        for (int s = 0; s < 2; s++) {
            const short8 pa = *(const short8*)&Ps[16*w + lr][32*s + 8*lg];
            #pragma unroll
            for (int g = 0; g < 4; g++) {
                const short8 vb = *(const short8*)&vt[(size_t)(16*g + lr)*S_ + 64*ch + 32*s + 8*lg];
                pv[g] = __builtin_amdgcn_mfma_f32_16x16x32_bf16(pa, vb, pv[g], 0, 0, 0);
            }
        }
        {   // vectorized prob writes from Ps (bf16 -> f32)
            const int rr = t >> 2, sg = (t & 3) * 16;
            float* prr = &pr[(size_t)(q0 + rr)*S_ + 64*ch + sg];
            #pragma unroll
            for (int jj = 0; jj < 2; jj++) {
                const short8 u = *(const short8*)&Ps[rr][sg + 8*jj];
                float4 f0, f1;
                f0.x = bf2f((unsigned short)u[0]); f0.y = bf2f((unsigned short)u[1]);
                f0.z = bf2f((unsigned short)u[2]); f0.w = bf2f((unsigned short)u[3]);
                f1.x = bf2f((unsigned short)u[4]); f1.y = bf2f((unsigned short)u[5]);
                f1.z = bf2f((unsigned short)u[6]); f1.w = bf2f((unsigned short)u[7]);
                *(float4*)&prr[8*jj]     = f0;
                *(float4*)&prr[8*jj + 4] = f1;
            }
        }
    }

    #pragma unroll
    for (int g = 0; g < 4; g++)
        #pragma unroll
        for (int i = 0; i < 4; i++)
            out[((size_t)(b*S_ + qrb + i))*D_ + h*DH_ + 16*g + lr] = pv[g][i];
}

// ---------------------------------------------------------------------------
extern "C" void kernel_launch(void* const* d_in, const int* in_sizes, int n_in,
                              void* d_out, int out_size, void* d_ws, size_t ws_size,
                              hipStream_t stream)
{
    const float* query = (const float*)d_in[0];
    const float* key   = (const float*)d_in[1];
    const float* value = (const float*)d_in[2];
    const float* rel   = (const float*)d_in[3];
    const float* tsp   = (const float*)d_in[4];
    const float* l1    = (const float*)d_in[5];
    const float* l2    = (const float*)d_in[6];
    // d_in[7]=mask (causal, recomputed), d_in[8]=encode_pos (unused)
    const float* Wq = (const float*)d_in[9];
    const float* bq = (const float*)d_in[10];
    const float* Wk = (const float*)d_in[11];
    const float* bk = (const float*)d_in[12];
    const float* Wv = (const float*)d_in[13];
    const float* bv = (const float*)d_in[14];
    // Wc/bc/Wg/bg (15..18): R1 constant along softmax axis -> cancels

    float* out  = (float*)d_out;
    float* prob = (float*)d_out + (size_t)B_ * S_ * D_;

    // Abf scratch lives in the prob region (written before attn overwrites it)
    unsigned short* Abf = (unsigned short*)prob;           // 3*4M bf16 = 25 MB

    const size_t headN = (size_t)B_ * H_ * S_ * DH_;       // 4,194,304
    unsigned short* Wbf = (unsigned short*)d_ws;           // 3*1M
    unsigned short* qw  = Wbf + 3*1048576;
    unsigned short* kw  = qw + headN;
    unsigned short* vw  = kw + headN;
    unsigned short* vtw = vw + headN;
    unsigned short* Ew  = vtw + headN;                     // B*S*S bf16 = 4.2 MB

    conv_bf16<<<2048, 256, 0, stream>>>(query, key, value, Wq, Wk, Wv, Abf, Wbf);

    qkv_gemm<<<768, 256, 0, stream>>>(Abf, Wbf, bq, bk, bv, qw, kw, vw);

    dim3 gt(8, B_ * H_);
    vtrans<<<gt, 256, 0, stream>>>(vw, vtw);

    e_kernel<<<(B_ * S_) / 4, 256, 0, stream>>>(rel, tsp, l1, l2, Ew);

    dim3 ga(S_ / 64, B_ * H_);
    attn_mfma<<<ga, 256, 0, stream>>>(qw, kw, vtw, Ew, l1, l2, out, prob);
}

// Round 5
// 143.119 us; speedup vs baseline: 6.5858x; 1.1175x over previous
//
#include <hip/hip_runtime.h>
#include <math.h>

typedef __attribute__((ext_vector_type(8))) short short8;
typedef __attribute__((ext_vector_type(4))) float f32x4;

#define B_  8
#define S_  512
#define D_  1024
#define H_  16
#define DH_ 64

__device__ __forceinline__ unsigned short f2bf(float f) {
    unsigned int u = __float_as_uint(f);
    u += 0x7FFFu + ((u >> 16) & 1u);      // round-to-nearest-even
    return (unsigned short)(u >> 16);
}
__device__ __forceinline__ float bf2f(unsigned short u) {
    return __uint_as_float(((unsigned int)u) << 16);
}
__device__ __forceinline__ void gload_lds16(const void* g, void* l) {
    __builtin_amdgcn_global_load_lds(
        (const __attribute__((address_space(1))) unsigned int*)g,
        (__attribute__((address_space(3))) unsigned int*)l, 16, 0, 0);
}

// ---------------------------------------------------------------------------
// f32 -> bf16 converter for the 6 GEMM operands (query,key,value,Wq,Wk,Wv).
// ---------------------------------------------------------------------------
__global__ __launch_bounds__(256) void conv_bf16(
    const float* __restrict__ q, const float* __restrict__ k, const float* __restrict__ v,
    const float* __restrict__ wq, const float* __restrict__ wk, const float* __restrict__ wv,
    unsigned short* __restrict__ Abf, unsigned short* __restrict__ Wbf)
{
    const size_t NA = 1048576;   // float4s per A tensor (4M elts / 4)
    const size_t NW = 262144;    // float4s per W tensor
    const size_t total = 3*NA + 3*NW;
    for (size_t i4 = (size_t)blockIdx.x*blockDim.x + threadIdx.x; i4 < total;
         i4 += (size_t)gridDim.x*blockDim.x) {
        const float* s; unsigned short* d; size_t off;
        if (i4 < 3*NA) {
            const int z = (int)(i4 / NA);
            s = (z == 0) ? q : (z == 1) ? k : v;
            off = i4 - (size_t)z*NA;
            d = Abf + (size_t)z*NA*4;
        } else {
            const size_t j = i4 - 3*NA;
            const int z = (int)(j / NW);
            s = (z == 0) ? wq : (z == 1) ? wk : wv;
            off = j - (size_t)z*NW;
            d = Wbf + (size_t)z*NW*4;
        }
        const float4 f = ((const float4*)s)[off];
        ushort4 u; u.x = f2bf(f.x); u.y = f2bf(f.y); u.z = f2bf(f.z); u.w = f2bf(f.w);
        ((ushort4*)d)[off] = u;
    }
}

// ---------------------------------------------------------------------------
// QKV projection GEMM, m97 structure (unchanged from R3).
// ---------------------------------------------------------------------------
__global__ __launch_bounds__(256) void qkv_gemm(
    const unsigned short* __restrict__ Abf, const unsigned short* __restrict__ Wbf,
    const float* __restrict__ bq, const float* __restrict__ bk, const float* __restrict__ bv,
    unsigned short* __restrict__ qw, unsigned short* __restrict__ kw,
    unsigned short* __restrict__ vw)
{
    __shared__ unsigned short As[128][64];   // 16 KB, content XOR-swizzled
    __shared__ unsigned short Bs[128][64];

    const int bid = blockIdx.x;
    const int wid = (bid & 7) * 96 + (bid >> 3);
    const int z   = wid >> 8;            // tensor
    const int rem = wid & 255;
    const int bm  = (rem >> 3) * 128;    // m-block
    const int bn  = (rem & 7) * 128;     // n-block

    const unsigned short* A = Abf + (size_t)z * 4194304;
    const unsigned short* W = Wbf + (size_t)z * 1048576;
    const float* bias = (z == 0) ? bq : (z == 1) ? bk : bv;
    unsigned short* outp = (z == 0) ? qw : (z == 1) ? kw : vw;
    const float scale = (z == 0) ? 0.125f : 1.0f;   // fold 1/sqrt(dh) into q

    const int t = threadIdx.x, w = t >> 6, l = t & 63, lr = l & 15, lg = l >> 4;
    const int wr = (w >> 1) * 64, wc = (w & 1) * 64;

    const int srow = t >> 3;                       // 0..31
    const int scol = 8 * ((t & 7) ^ (srow & 7));   // pre-swizzled source col
    const unsigned short* Ast = A + (size_t)(bm + srow) * 1024 + scol;
    const unsigned short* Wst = W + (size_t)(bn + srow) * 1024 + scol;
    char* AsB = (char*)As; char* BsB = (char*)Bs;

    f32x4 acc[4][4] = {};
    for (int k0 = 0; k0 < 1024; k0 += 64) {
        __syncthreads();
        #pragma unroll
        for (int j = 0; j < 4; j++) {
            gload_lds16(Ast + (size_t)(32*j)*1024 + k0, AsB + 4096*j + t*16);
            gload_lds16(Wst + (size_t)(32*j)*1024 + k0, BsB + 4096*j + t*16);
        }
        __syncthreads();
        #pragma unroll
        for (int s = 0; s < 2; s++) {
            short8 af[4], bf4[4];
            #pragma unroll
            for (int i = 0; i < 4; i++) {
                const int row = wr + 16*i + lr;
                af[i] = *(const short8*)(AsB + row*128 + (((4*s + lg) ^ (row & 7)) << 4));
            }
            #pragma unroll
            for (int j = 0; j < 4; j++) {
                const int row = wc + 16*j + lr;
                bf4[j] = *(const short8*)(BsB + row*128 + (((4*s + lg) ^ (row & 7)) << 4));
            }
            #pragma unroll
            for (int i = 0; i < 4; i++)
                #pragma unroll
                for (int j = 0; j < 4; j++)
                    acc[i][j] = __builtin_amdgcn_mfma_f32_16x16x32_bf16(af[i], bf4[j], acc[i][j], 0, 0, 0);
        }
    }

    #pragma unroll
    for (int j = 0; j < 4; j++) {
        const int n = bn + wc + 16*j + lr;
        const float bvx = bias[n];
        const int h = n >> 6, dh = n & 63;
        #pragma unroll
        for (int i = 0; i < 4; i++)
            #pragma unroll
            for (int r = 0; r < 4; r++) {
                const int m = bm + wr + 16*i + 4*lg + r;     // D row = 4*(l>>4)+reg
                const int bb = m >> 9, s = m & 511;
                outp[(((size_t)(bb*H_ + h))*S_ + s)*DH_ + dh] = f2bf((acc[i][j][r] + bvx) * scale);
            }
    }
}

// ---------------------------------------------------------------------------
// V transpose: vtw[bh][dh][s] = vw[bh][s][dh].
// ---------------------------------------------------------------------------
__global__ __launch_bounds__(256) void vtrans(const unsigned short* __restrict__ vw,
                                              unsigned short* __restrict__ vtw)
{
    __shared__ unsigned short tile[64][68];
    const int bh = blockIdx.y, sc = blockIdx.x * 64;
    const unsigned short* src = vw + (size_t)bh * S_ * DH_;
    unsigned short* dst = vtw + (size_t)bh * DH_ * S_;
    const int t = threadIdx.x;
    const int r = t >> 4, c4 = (t & 15) << 2;
    #pragma unroll
    for (int i = 0; i < 4; i++)
        *(ushort4*)&tile[r + 16*i][c4] = *(const ushort4*)&src[(size_t)(sc + r + 16*i)*DH_ + c4];
    __syncthreads();
    const int dh = t >> 2, sg = (t & 3) * 16;
    #pragma unroll
    for (int e = 0; e < 16; e += 4) {
        ushort4 u;
        u.x = tile[sg + e + 0][dh]; u.y = tile[sg + e + 1][dh];
        u.z = tile[sg + e + 2][dh]; u.w = tile[sg + e + 3][dh];
        *(ushort4*)&dst[(size_t)dh*S_ + sc + sg + e] = u;
    }
}

// ---------------------------------------------------------------------------
// E[b][q][k] = c_t*time_attn + c_r*rel_attn  (head-independent), bf16 out.
// ---------------------------------------------------------------------------
__global__ __launch_bounds__(256) void e_kernel(
    const float* __restrict__ rel, const float* __restrict__ tsp,
    const float* __restrict__ pl1, const float* __restrict__ pl2,
    unsigned short* __restrict__ E)
{
    const int t = threadIdx.x, w = t >> 6, l = t & 63;
    const int ridx = blockIdx.x * 4 + w;        // b*S + q
    const int q = ridx & (S_ - 1);
    const float l1 = *pl1, l2 = *pl2;
    const float c_t = (1.f - l1) * l2, c_r = l1;
    const float* tr = tsp + (size_t)ridx * S_;
    const float* rr = rel + (size_t)ridx * S_;

    float tv[8], rv[8]; float st = 0.f, sr = 0.f;
    #pragma unroll
    for (int j = 0; j < 8; j++) {
        const int k = l + 64*j;
        const float rvv = rr[k];
        rv[j] = (rvv != 0.f) ? __expf(rvv) : 0.f;   // exp(-10000)==0 exactly
        sr += rv[j];
        float tvv = 0.f;
        if (k <= q) tvv = __expf(__expf(-fabsf(tr[k])));
        tv[j] = tvv; st += tvv;
    }
    #pragma unroll
    for (int m = 32; m; m >>= 1) { st += __shfl_xor(st, m); sr += __shfl_xor(sr, m); }
    const float ti   = c_t / st;
    const float riv  = (sr > 0.f) ? c_r / sr : 0.f;
    const float runi = (sr > 0.f) ? 0.f : c_r / (float)S_;

    unsigned short* Er = E + (size_t)ridx * S_;
    #pragma unroll
    for (int j = 0; j < 8; j++) {
        const int k = l + 64*j;
        Er[k] = f2bf(tv[j]*ti + rv[j]*riv + runi);
    }
}

// ---------------------------------------------------------------------------
// Fused attention. 1D grid 1024; XCD-locality swizzle: bid&7 == batch b, so
// each XCD works on exactly one batch (16 heads x Q/K/V + E[b] ~= 3.5 MB,
// fits its private 4 MB L2). Pass 2: prob stored DIRECTLY from registers
// (f32); Ps (bf16) kept only as PV MFMA A-operand, double-buffered so each
// chunk needs ONE barrier.
// ---------------------------------------------------------------------------
__global__ __launch_bounds__(256) void attn_mfma(
    const unsigned short* __restrict__ qw, const unsigned short* __restrict__ kw,
    const unsigned short* __restrict__ vtw, const unsigned short* __restrict__ E,
    const float* __restrict__ pl1, const float* __restrict__ pl2,
    float* __restrict__ out, float* __restrict__ prob)
{
    __shared__ unsigned short Ps[2][64][72];

    const int t = threadIdx.x, w = t >> 6, l = t & 63, lr = l & 15, lg = l >> 4;
    const int bid = blockIdx.x;
    const int j   = bid >> 3;
    const int bh  = (bid & 7) * 16 + (j & 15);     // b = bid&7, h = j&15
    const int b   = bh >> 4, h = bh & 15;
    const int q0  = (j >> 4) * 64;
    const float l1 = *pl1, l2 = *pl2;
    const float c_p = (1.f - l1) * (1.f - l2);
    const unsigned short* qp = qw + (size_t)bh * (S_ * DH_);
    const unsigned short* kp = kw + (size_t)bh * (S_ * DH_);
    const unsigned short* vt = vtw + (size_t)bh * (DH_ * S_);

    short8 qa[2];
    #pragma unroll
    for (int s = 0; s < 2; s++)
        qa[s] = *(const short8*)&qp[(size_t)(q0 + 16*w + lr)*DH_ + 32*s + 8*lg];

    const int qrb = q0 + 16*w + 4*lg;    // +i = absolute q row for acc elem i

    // ---- pass 1: QK^T, pack scores (bf16 pairs) with causal mask ----
    unsigned int scp[8][4][2];
    #pragma unroll
    for (int ch = 0; ch < 8; ch++) {
        f32x4 a4[4] = {};
        #pragma unroll
        for (int s = 0; s < 2; s++)
            #pragma unroll
            for (int g = 0; g < 4; g++) {
                const short8 kb = *(const short8*)&kp[(size_t)(ch*64 + 16*g + lr)*DH_ + 32*s + 8*lg];
                a4[g] = __builtin_amdgcn_mfma_f32_16x16x32_bf16(qa[s], kb, a4[g], 0, 0, 0);
            }
        #pragma unroll
        for (int g = 0; g < 4; g++) {
            const int k = 64*ch + 16*g + lr;
            const float v0 = (k <= qrb + 0) ? a4[g][0] : -1e30f;
            const float v1 = (k <= qrb + 1) ? a4[g][1] : -1e30f;
            const float v2 = (k <= qrb + 2) ? a4[g][2] : -1e30f;
            const float v3 = (k <= qrb + 3) ? a4[g][3] : -1e30f;
            scp[ch][g][0] = ((unsigned)f2bf(v1) << 16) | f2bf(v0);
            scp[ch][g][1] = ((unsigned)f2bf(v3) << 16) | f2bf(v2);
        }
    }

    // ---- softmax over packed scores ----
    float mx[4] = {-1e30f, -1e30f, -1e30f, -1e30f};
    #pragma unroll
    for (int ch = 0; ch < 8; ch++)
        #pragma unroll
        for (int g = 0; g < 4; g++) {
            const unsigned u0 = scp[ch][g][0], u1 = scp[ch][g][1];
            mx[0] = fmaxf(mx[0], __uint_as_float(u0 << 16));
            mx[1] = fmaxf(mx[1], __uint_as_float(u0 & 0xffff0000u));
            mx[2] = fmaxf(mx[2], __uint_as_float(u1 << 16));
            mx[3] = fmaxf(mx[3], __uint_as_float(u1 & 0xffff0000u));
        }
    #pragma unroll
    for (int i = 0; i < 4; i++)
        #pragma unroll
        for (int m = 8; m; m >>= 1) mx[i] = fmaxf(mx[i], __shfl_xor(mx[i], m));

    float sm[4] = {0.f, 0.f, 0.f, 0.f};
    #pragma unroll
    for (int ch = 0; ch < 8; ch++)
        #pragma unroll
        for (int g = 0; g < 4; g++) {
            const unsigned u0 = scp[ch][g][0], u1 = scp[ch][g][1];
            const float e0 = __expf(__uint_as_float(u0 << 16)          - mx[0]);
            const float e1 = __expf(__uint_as_float(u0 & 0xffff0000u) - mx[1]);
            const float e2 = __expf(__uint_as_float(u1 << 16)          - mx[2]);
            const float e3 = __expf(__uint_as_float(u1 & 0xffff0000u) - mx[3]);
            sm[0] += e0; sm[1] += e1; sm[2] += e2; sm[3] += e3;
            scp[ch][g][0] = ((unsigned)f2bf(e1) << 16) | f2bf(e0);
            scp[ch][g][1] = ((unsigned)f2bf(e3) << 16) | f2bf(e2);
        }
    #pragma unroll
    for (int i = 0; i < 4; i++)
        #pragma unroll
        for (int m = 8; m; m >>= 1) sm[i] += __shfl_xor(sm[i], m);
    float pinv[4];
    #pragma unroll
    for (int i = 0; i < 4; i++) pinv[i] = c_p / sm[i];

    // ---- pass 2: fin -> Ps (dbuf) + direct prob stores; PV MFMA ----
    f32x4 pv[4] = {};
    const unsigned short* Eb = E + ((size_t)b * S_ + qrb) * S_;
    float* pr = prob + ((size_t)bh * S_ + qrb) * S_;
    const int prow = 16*w + 4*lg;

    #pragma unroll
    for (int ch = 0; ch < 8; ch++) {
        const int p = ch & 1;
        #pragma unroll
        for (int g = 0; g < 4; g++) {
            const int kc = 16*g + lr;
            const unsigned u0 = scp[ch][g][0], u1 = scp[ch][g][1];
            const size_t eb = (size_t)(64*ch + kc);
            const float f0 = __uint_as_float(u0 << 16)          * pinv[0] + bf2f(Eb[eb]);
            const float f1 = __uint_as_float(u0 & 0xffff0000u) * pinv[1] + bf2f(Eb[eb + 512]);
            const float f2 = __uint_as_float(u1 << 16)          * pinv[2] + bf2f(Eb[eb + 1024]);
            const float f3 = __uint_as_float(u1 & 0xffff0000u) * pinv[3] + bf2f(Eb[eb + 1536]);
            Ps[p][prow + 0][kc] = f2bf(f0);
            Ps[p][prow + 1][kc] = f2bf(f1);
            Ps[p][prow + 2][kc] = f2bf(f2);
            Ps[p][prow + 3][kc] = f2bf(f3);
            pr[eb]        = f0;
            pr[eb + 512]  = f1;
            pr[eb + 1024] = f2;
            pr[eb + 1536] = f3;
        }
        __syncthreads();
        #pragma unroll
        for (int s = 0; s < 2; s++) {
            const short8 pa = *(const short8*)&Ps[p][16*w + lr][32*s + 8*lg];
            #pragma unroll
            for (int g = 0; g < 4; g++) {
                const short8 vb = *(const short8*)&vt[(size_t)(16*g + lr)*S_ + 64*ch + 32*s + 8*lg];
                pv[g] = __builtin_amdgcn_mfma_f32_16x16x32_bf16(pa, vb, pv[g], 0, 0, 0);
            }
        }
    }

    #pragma unroll
    for (int g = 0; g < 4; g++)
        #pragma unroll
        for (int i = 0; i < 4; i++)
            out[((size_t)(b*S_ + qrb + i))*D_ + h*DH_ + 16*g + lr] = pv[g][i];
}

// ---------------------------------------------------------------------------
extern "C" void kernel_launch(void* const* d_in, const int* in_sizes, int n_in,
                              void* d_out, int out_size, void* d_ws, size_t ws_size,
                              hipStream_t stream)
{
    const float* query = (const float*)d_in[0];
    const float* key   = (const float*)d_in[1];
    const float* value = (const float*)d_in[2];
    const float* rel   = (const float*)d_in[3];
    const float* tsp   = (const float*)d_in[4];
    const float* l1    = (const float*)d_in[5];
    const float* l2    = (const float*)d_in[6];
    // d_in[7]=mask (causal, recomputed), d_in[8]=encode_pos (unused)
    const float* Wq = (const float*)d_in[9];
    const float* bq = (const float*)d_in[10];
    const float* Wk = (const float*)d_in[11];
    const float* bk = (const float*)d_in[12];
    const float* Wv = (const float*)d_in[13];
    const float* bv = (const float*)d_in[14];
    // Wc/bc/Wg/bg (15..18): R1 constant along softmax axis -> cancels

    float* out  = (float*)d_out;
    float* prob = (float*)d_out + (size_t)B_ * S_ * D_;

    // Abf scratch lives in the prob region (written before attn overwrites it)
    unsigned short* Abf = (unsigned short*)prob;           // 3*4M bf16 = 25 MB

    const size_t headN = (size_t)B_ * H_ * S_ * DH_;       // 4,194,304
    unsigned short* Wbf = (unsigned short*)d_ws;           // 3*1M
    unsigned short* qw  = Wbf + 3*1048576;
    unsigned short* kw  = qw + headN;
    unsigned short* vw  = kw + headN;
    unsigned short* vtw = vw + headN;
    unsigned short* Ew  = vtw + headN;                     // B*S*S bf16 = 4.2 MB

    conv_bf16<<<2048, 256, 0, stream>>>(query, key, value, Wq, Wk, Wv, Abf, Wbf);

    qkv_gemm<<<768, 256, 0, stream>>>(Abf, Wbf, bq, bk, bv, qw, kw, vw);

    dim3 gt(8, B_ * H_);
    vtrans<<<gt, 256, 0, stream>>>(vw, vtw);

    e_kernel<<<(B_ * S_) / 4, 256, 0, stream>>>(rel, tsp, l1, l2, Ew);

    attn_mfma<<<1024, 256, 0, stream>>>(qw, kw, vtw, Ew, l1, l2, out, prob);
}

// Round 6
// 140.948 us; speedup vs baseline: 6.6872x; 1.0154x over previous
//
#include <hip/hip_runtime.h>
#include <math.h>

typedef __attribute__((ext_vector_type(8))) short short8;
typedef __attribute__((ext_vector_type(4))) float f32x4;

#define B_  8
#define S_  512
#define D_  1024
#define H_  16
#define DH_ 64

__device__ __forceinline__ unsigned short f2bf(float f) {
    unsigned int u = __float_as_uint(f);
    u += 0x7FFFu + ((u >> 16) & 1u);      // round-to-nearest-even
    return (unsigned short)(u >> 16);
}
__device__ __forceinline__ float bf2f(unsigned short u) {
    return __uint_as_float(((unsigned int)u) << 16);
}
// 2x f32 -> packed bf16 (RNE), lo in low 16 bits
__device__ __forceinline__ unsigned cvtpk(float lo, float hi) {
    unsigned r;
    asm("v_cvt_pk_bf16_f32 %0, %1, %2" : "=v"(r) : "v"(lo), "v"(hi));
    return r;
}

// ---------------------------------------------------------------------------
// Fused QKV projection GEMM: reads f32 A (query/key/value) and f32 W directly,
// converts to bf16 in-register during staging (v_cvt_pk_bf16_f32), stages via
// swizzled ds_write_b128 (LDS content identical to R3/R4 scheme: 16B block p
// of row holds k-chunk p^(row&7)), MFMA read side unchanged.
// z==0/1: writes q/k in head layout [bh][s][dh] (scale 0.125 folded into q).
// z==2:   writes V DIRECTLY TRANSPOSED [bh][dh][s] (ushort4, 4 consecutive s).
// 1D grid 768 = 3(z) * 32(my) * 8(nx), XCD-bijective swizzle (768%8==0).
// ---------------------------------------------------------------------------
__global__ __launch_bounds__(256) void qkv_gemm(
    const float* __restrict__ Aq, const float* __restrict__ Ak, const float* __restrict__ Av,
    const float* __restrict__ Wq, const float* __restrict__ Wk, const float* __restrict__ Wv,
    const float* __restrict__ bq, const float* __restrict__ bk, const float* __restrict__ bv,
    unsigned short* __restrict__ qw, unsigned short* __restrict__ kw,
    unsigned short* __restrict__ vtw)
{
    __shared__ unsigned short As[128][64];   // 16 KB, content XOR-swizzled
    __shared__ unsigned short Bs[128][64];

    const int bid = blockIdx.x;
    const int wid = (bid & 7) * 96 + (bid >> 3);
    const int z   = wid >> 8;            // tensor
    const int rem = wid & 255;
    const int bm  = (rem >> 3) * 128;    // m-block
    const int bn  = (rem & 7) * 128;     // n-block

    const float* A = (z == 0) ? Aq : (z == 1) ? Ak : Av;
    const float* W = (z == 0) ? Wq : (z == 1) ? Wk : Wv;
    const float* bias = (z == 0) ? bq : (z == 1) ? bk : bv;
    const float scale = (z == 0) ? 0.125f : 1.0f;   // fold 1/sqrt(dh) into q

    const int t = threadIdx.x, w = t >> 6, l = t & 63, lr = l & 15, lg = l >> 4;
    const int wr = (w >> 1) * 64, wc = (w & 1) * 64;

    const int srow = t >> 3;             // 0..31 (row within 32-row group)
    const int sblk = t & 7;              // 8-float k-chunk
    char* AsB = (char*)As; char* BsB = (char*)Bs;

    f32x4 acc[4][4] = {};
    for (int k0 = 0; k0 < 1024; k0 += 64) {
        __syncthreads();                 // prev tile fully consumed
        float4 av[4][2], wv4[4][2];
        #pragma unroll
        for (int j = 0; j < 4; j++) {
            const float* ap = A + (size_t)(bm + 32*j + srow)*1024 + k0 + sblk*8;
            const float* wp = W + (size_t)(bn + 32*j + srow)*1024 + k0 + sblk*8;
            av[j][0]  = ((const float4*)ap)[0]; av[j][1]  = ((const float4*)ap)[1];
            wv4[j][0] = ((const float4*)wp)[0]; wv4[j][1] = ((const float4*)wp)[1];
        }
        #pragma unroll
        for (int j = 0; j < 4; j++) {
            const int row = 32*j + srow;
            const int byte = row*128 + ((sblk ^ (row & 7)) << 4);
            uint4 ua, uw;
            ua.x = cvtpk(av[j][0].x, av[j][0].y);  ua.y = cvtpk(av[j][0].z, av[j][0].w);
            ua.z = cvtpk(av[j][1].x, av[j][1].y);  ua.w = cvtpk(av[j][1].z, av[j][1].w);
            uw.x = cvtpk(wv4[j][0].x, wv4[j][0].y); uw.y = cvtpk(wv4[j][0].z, wv4[j][0].w);
            uw.z = cvtpk(wv4[j][1].x, wv4[j][1].y); uw.w = cvtpk(wv4[j][1].z, wv4[j][1].w);
            *(uint4*)(AsB + byte) = ua;
            *(uint4*)(BsB + byte) = uw;
        }
        __syncthreads();
        #pragma unroll
        for (int s = 0; s < 2; s++) {
            short8 af[4], bf4[4];
            #pragma unroll
            for (int i = 0; i < 4; i++) {
                const int row = wr + 16*i + lr;
                af[i] = *(const short8*)(AsB + row*128 + (((4*s + lg) ^ (row & 7)) << 4));
            }
            #pragma unroll
            for (int j = 0; j < 4; j++) {
                const int row = wc + 16*j + lr;
                bf4[j] = *(const short8*)(BsB + row*128 + (((4*s + lg) ^ (row & 7)) << 4));
            }
            #pragma unroll
            for (int i = 0; i < 4; i++)
                #pragma unroll
                for (int j = 0; j < 4; j++)
                    acc[i][j] = __builtin_amdgcn_mfma_f32_16x16x32_bf16(af[i], bf4[j], acc[i][j], 0, 0, 0);
        }
    }

    if (z < 2) {
        unsigned short* outp = (z == 0) ? qw : kw;
        #pragma unroll
        for (int j = 0; j < 4; j++) {
            const int n = bn + wc + 16*j + lr;
            const float bvx = bias[n];
            const int h = n >> 6, dh = n & 63;
            #pragma unroll
            for (int i = 0; i < 4; i++)
                #pragma unroll
                for (int r = 0; r < 4; r++) {
                    const int m = bm + wr + 16*i + 4*lg + r;   // D row = 4*(l>>4)+reg
                    const int bb = m >> 9, s = m & 511;
                    outp[(((size_t)(bb*H_ + h))*S_ + s)*DH_ + dh] = f2bf((acc[i][j][r] + bvx) * scale);
                }
        }
    } else {
        // V: write transposed [bh][dh][s]; r -> consecutive s -> ushort4
        #pragma unroll
        for (int j = 0; j < 4; j++) {
            const int n = bn + wc + 16*j + lr;
            const float bvx = bias[n];
            const int h = n >> 6, dh = n & 63;
            #pragma unroll
            for (int i = 0; i < 4; i++) {
                const int m0 = bm + wr + 16*i + 4*lg;          // s0 = m0&511 (4-aligned)
                const int bb = m0 >> 9, s0 = m0 & 511;
                ushort4 u;
                u.x = f2bf(acc[i][j][0] + bvx); u.y = f2bf(acc[i][j][1] + bvx);
                u.z = f2bf(acc[i][j][2] + bvx); u.w = f2bf(acc[i][j][3] + bvx);
                *(ushort4*)&vtw[(((size_t)(bb*H_ + h))*DH_ + dh)*S_ + s0] = u;
            }
        }
    }
}

// ---------------------------------------------------------------------------
// E[b][q][k] = c_t*time_attn + c_r*rel_attn  (head-independent), bf16 out.
// R1 = sigmoid(gf-cf)+gf is constant along k -> cancels in softmax.
// ---------------------------------------------------------------------------
__global__ __launch_bounds__(256) void e_kernel(
    const float* __restrict__ rel, const float* __restrict__ tsp,
    const float* __restrict__ pl1, const float* __restrict__ pl2,
    unsigned short* __restrict__ E)
{
    const int t = threadIdx.x, w = t >> 6, l = t & 63;
    const int ridx = blockIdx.x * 4 + w;        // b*S + q
    const int q = ridx & (S_ - 1);
    const float l1 = *pl1, l2 = *pl2;
    const float c_t = (1.f - l1) * l2, c_r = l1;
    const float* tr = tsp + (size_t)ridx * S_;
    const float* rr = rel + (size_t)ridx * S_;

    float tv[8], rv[8]; float st = 0.f, sr = 0.f;
    #pragma unroll
    for (int j = 0; j < 8; j++) {
        const int k = l + 64*j;
        const float rvv = rr[k];
        rv[j] = (rvv != 0.f) ? __expf(rvv) : 0.f;   // exp(-10000)==0 exactly
        sr += rv[j];
        float tvv = 0.f;
        if (k <= q) tvv = __expf(__expf(-fabsf(tr[k])));
        tv[j] = tvv; st += tvv;
    }
    #pragma unroll
    for (int m = 32; m; m >>= 1) { st += __shfl_xor(st, m); sr += __shfl_xor(sr, m); }
    const float ti   = c_t / st;
    const float riv  = (sr > 0.f) ? c_r / sr : 0.f;
    const float runi = (sr > 0.f) ? 0.f : c_r / (float)S_;

    unsigned short* Er = E + (size_t)ridx * S_;
    #pragma unroll
    for (int j = 0; j < 8; j++) {
        const int k = l + 64*j;
        Er[k] = f2bf(tv[j]*ti + rv[j]*riv + runi);
    }
}

// ---------------------------------------------------------------------------
// Fused attention. 1D grid 1024; XCD-locality: bid&7 == batch b. prob/out
// stored NONTEMPORAL (streaming, never re-read) to keep K/V/E L2-resident.
// ---------------------------------------------------------------------------
__global__ __launch_bounds__(256) void attn_mfma(
    const unsigned short* __restrict__ qw, const unsigned short* __restrict__ kw,
    const unsigned short* __restrict__ vtw, const unsigned short* __restrict__ E,
    const float* __restrict__ pl1, const float* __restrict__ pl2,
    float* __restrict__ out, float* __restrict__ prob)
{
    __shared__ unsigned short Ps[2][64][72];

    const int t = threadIdx.x, w = t >> 6, l = t & 63, lr = l & 15, lg = l >> 4;
    const int bid = blockIdx.x;
    const int j   = bid >> 3;
    const int bh  = (bid & 7) * 16 + (j & 15);     // b = bid&7, h = j&15
    const int b   = bh >> 4, h = bh & 15;
    const int q0  = (j >> 4) * 64;
    const float l1 = *pl1, l2 = *pl2;
    const float c_p = (1.f - l1) * (1.f - l2);
    const unsigned short* qp = qw + (size_t)bh * (S_ * DH_);
    const unsigned short* kp = kw + (size_t)bh * (S_ * DH_);
    const unsigned short* vt = vtw + (size_t)bh * (DH_ * S_);

    short8 qa[2];
    #pragma unroll
    for (int s = 0; s < 2; s++)
        qa[s] = *(const short8*)&qp[(size_t)(q0 + 16*w + lr)*DH_ + 32*s + 8*lg];

    const int qrb = q0 + 16*w + 4*lg;    // +i = absolute q row for acc elem i

    // ---- pass 1: QK^T, pack scores (bf16 pairs) with causal mask ----
    unsigned int scp[8][4][2];
    #pragma unroll
    for (int ch = 0; ch < 8; ch++) {
        f32x4 a4[4] = {};
        #pragma unroll
        for (int s = 0; s < 2; s++)
            #pragma unroll
            for (int g = 0; g < 4; g++) {
                const short8 kb = *(const short8*)&kp[(size_t)(ch*64 + 16*g + lr)*DH_ + 32*s + 8*lg];
                a4[g] = __builtin_amdgcn_mfma_f32_16x16x32_bf16(qa[s], kb, a4[g], 0, 0, 0);
            }
        #pragma unroll
        for (int g = 0; g < 4; g++) {
            const int k = 64*ch + 16*g + lr;
            const float v0 = (k <= qrb + 0) ? a4[g][0] : -1e30f;
            const float v1 = (k <= qrb + 1) ? a4[g][1] : -1e30f;
            const float v2 = (k <= qrb + 2) ? a4[g][2] : -1e30f;
            const float v3 = (k <= qrb + 3) ? a4[g][3] : -1e30f;
            scp[ch][g][0] = ((unsigned)f2bf(v1) << 16) | f2bf(v0);
            scp[ch][g][1] = ((unsigned)f2bf(v3) << 16) | f2bf(v2);
        }
    }

    // ---- softmax over packed scores ----
    float mx[4] = {-1e30f, -1e30f, -1e30f, -1e30f};
    #pragma unroll
    for (int ch = 0; ch < 8; ch++)
        #pragma unroll
        for (int g = 0; g < 4; g++) {
            const unsigned u0 = scp[ch][g][0], u1 = scp[ch][g][1];
            mx[0] = fmaxf(mx[0], __uint_as_float(u0 << 16));
            mx[1] = fmaxf(mx[1], __uint_as_float(u0 & 0xffff0000u));
            mx[2] = fmaxf(mx[2], __uint_as_float(u1 << 16));
            mx[3] = fmaxf(mx[3], __uint_as_float(u1 & 0xffff0000u));
        }
    #pragma unroll
    for (int i = 0; i < 4; i++)
        #pragma unroll
        for (int m = 8; m; m >>= 1) mx[i] = fmaxf(mx[i], __shfl_xor(mx[i], m));

    float sm[4] = {0.f, 0.f, 0.f, 0.f};
    #pragma unroll
    for (int ch = 0; ch < 8; ch++)
        #pragma unroll
        for (int g = 0; g < 4; g++) {
            const unsigned u0 = scp[ch][g][0], u1 = scp[ch][g][1];
            const float e0 = __expf(__uint_as_float(u0 << 16)          - mx[0]);
            const float e1 = __expf(__uint_as_float(u0 & 0xffff0000u) - mx[1]);
            const float e2 = __expf(__uint_as_float(u1 << 16)          - mx[2]);
            const float e3 = __expf(__uint_as_float(u1 & 0xffff0000u) - mx[3]);
            sm[0] += e0; sm[1] += e1; sm[2] += e2; sm[3] += e3;
            scp[ch][g][0] = ((unsigned)f2bf(e1) << 16) | f2bf(e0);
            scp[ch][g][1] = ((unsigned)f2bf(e3) << 16) | f2bf(e2);
        }
    #pragma unroll
    for (int i = 0; i < 4; i++)
        #pragma unroll
        for (int m = 8; m; m >>= 1) sm[i] += __shfl_xor(sm[i], m);
    float pinv[4];
    #pragma unroll
    for (int i = 0; i < 4; i++) pinv[i] = c_p / sm[i];

    // ---- pass 2: fin -> Ps (dbuf) + nontemporal prob stores; PV MFMA ----
    f32x4 pv[4] = {};
    const unsigned short* Eb = E + ((size_t)b * S_ + qrb) * S_;
    float* pr = prob + ((size_t)bh * S_ + qrb) * S_;
    const int prow = 16*w + 4*lg;

    #pragma unroll
    for (int ch = 0; ch < 8; ch++) {
        const int p = ch & 1;
        #pragma unroll
        for (int g = 0; g < 4; g++) {
            const int kc = 16*g + lr;
            const unsigned u0 = scp[ch][g][0], u1 = scp[ch][g][1];
            const size_t eb = (size_t)(64*ch + kc);
            const float f0 = __uint_as_float(u0 << 16)          * pinv[0] + bf2f(Eb[eb]);
            const float f1 = __uint_as_float(u0 & 0xffff0000u) * pinv[1] + bf2f(Eb[eb + 512]);
            const float f2 = __uint_as_float(u1 << 16)          * pinv[2] + bf2f(Eb[eb + 1024]);
            const float f3 = __uint_as_float(u1 & 0xffff0000u) * pinv[3] + bf2f(Eb[eb + 1536]);
            Ps[p][prow + 0][kc] = f2bf(f0);
            Ps[p][prow + 1][kc] = f2bf(f1);
            Ps[p][prow + 2][kc] = f2bf(f2);
            Ps[p][prow + 3][kc] = f2bf(f3);
            __builtin_nontemporal_store(f0, &pr[eb]);
            __builtin_nontemporal_store(f1, &pr[eb + 512]);
            __builtin_nontemporal_store(f2, &pr[eb + 1024]);
            __builtin_nontemporal_store(f3, &pr[eb + 1536]);
        }
        __syncthreads();
        #pragma unroll
        for (int s = 0; s < 2; s++) {
            const short8 pa = *(const short8*)&Ps[p][16*w + lr][32*s + 8*lg];
            #pragma unroll
            for (int g = 0; g < 4; g++) {
                const short8 vb = *(const short8*)&vt[(size_t)(16*g + lr)*S_ + 64*ch + 32*s + 8*lg];
                pv[g] = __builtin_amdgcn_mfma_f32_16x16x32_bf16(pa, vb, pv[g], 0, 0, 0);
            }
        }
    }

    #pragma unroll
    for (int g = 0; g < 4; g++)
        #pragma unroll
        for (int i = 0; i < 4; i++)
            __builtin_nontemporal_store(pv[g][i],
                &out[((size_t)(b*S_ + qrb + i))*D_ + h*DH_ + 16*g + lr]);
}

// ---------------------------------------------------------------------------
extern "C" void kernel_launch(void* const* d_in, const int* in_sizes, int n_in,
                              void* d_out, int out_size, void* d_ws, size_t ws_size,
                              hipStream_t stream)
{
    const float* query = (const float*)d_in[0];
    const float* key   = (const float*)d_in[1];
    const float* value = (const float*)d_in[2];
    const float* rel   = (const float*)d_in[3];
    const float* tsp   = (const float*)d_in[4];
    const float* l1    = (const float*)d_in[5];
    const float* l2    = (const float*)d_in[6];
    // d_in[7]=mask (causal, recomputed), d_in[8]=encode_pos (unused)
    const float* Wq = (const float*)d_in[9];
    const float* bq = (const float*)d_in[10];
    const float* Wk = (const float*)d_in[11];
    const float* bk = (const float*)d_in[12];
    const float* Wv = (const float*)d_in[13];
    const float* bv = (const float*)d_in[14];
    // Wc/bc/Wg/bg (15..18): R1 constant along softmax axis -> cancels

    float* out  = (float*)d_out;
    float* prob = (float*)d_out + (size_t)B_ * S_ * D_;

    const size_t headN = (size_t)B_ * H_ * S_ * DH_;       // 4,194,304
    unsigned short* qw  = (unsigned short*)d_ws;
    unsigned short* kw  = qw + headN;
    unsigned short* vtw = kw + headN;
    unsigned short* Ew  = vtw + headN;                     // B*S*S bf16 = 4.2 MB

    qkv_gemm<<<768, 256, 0, stream>>>(query, key, value, Wq, Wk, Wv,
                                      bq, bk, bv, qw, kw, vtw);

    e_kernel<<<(B_ * S_) / 4, 256, 0, stream>>>(rel, tsp, l1, l2, Ew);

    attn_mfma<<<1024, 256, 0, stream>>>(qw, kw, vtw, Ew, l1, l2, out, prob);
}

// Round 7
// 129.598 us; speedup vs baseline: 7.2729x; 1.0876x over previous
//
#include <hip/hip_runtime.h>
#include <math.h>

typedef __attribute__((ext_vector_type(8))) short short8;
typedef __attribute__((ext_vector_type(4))) float f32x4;

#define B_  8
#define S_  512
#define D_  1024
#define H_  16
#define DH_ 64

__device__ __forceinline__ unsigned short f2bf(float f) {
    unsigned int u = __float_as_uint(f);
    u += 0x7FFFu + ((u >> 16) & 1u);      // round-to-nearest-even
    return (unsigned short)(u >> 16);
}
__device__ __forceinline__ float bf2f(unsigned short u) {
    return __uint_as_float(((unsigned int)u) << 16);
}
// 2x f32 -> packed bf16 (RNE), lo in low 16 bits
__device__ __forceinline__ unsigned cvtpk(float lo, float hi) {
    unsigned r;
    asm("v_cvt_pk_bf16_f32 %0, %1, %2" : "=v"(r) : "v"(lo), "v"(hi));
    return r;
}

// ---------------------------------------------------------------------------
// Fused QKV projection GEMM with T14 software pipeline: tile t+1's global
// loads are issued right after tile t's cvt consumes the staging registers,
// so the vmcnt wait lands at the NEXT iteration's cvt — load latency hides
// under ds_write + barrier + 32 MFMAs + barrier.
// z==0/1: q/k in head layout [bh][s][dh] (0.125 folded into q).
// z==2:   V directly transposed [bh][dh][s] (ushort4 stores).
// 1D grid 768, XCD-bijective swizzle (768%8==0).
// ---------------------------------------------------------------------------
__global__ __launch_bounds__(256) void qkv_gemm(
    const float* __restrict__ Aq, const float* __restrict__ Ak, const float* __restrict__ Av,
    const float* __restrict__ Wq, const float* __restrict__ Wk, const float* __restrict__ Wv,
    const float* __restrict__ bq, const float* __restrict__ bk, const float* __restrict__ bv,
    unsigned short* __restrict__ qw, unsigned short* __restrict__ kw,
    unsigned short* __restrict__ vtw)
{
    __shared__ unsigned short As[128][64];   // 16 KB, content XOR-swizzled
    __shared__ unsigned short Bs[128][64];

    const int bid = blockIdx.x;
    const int wid = (bid & 7) * 96 + (bid >> 3);
    const int z   = wid >> 8;            // tensor
    const int rem = wid & 255;
    const int bm  = (rem >> 3) * 128;    // m-block
    const int bn  = (rem & 7) * 128;     // n-block

    const float* A = (z == 0) ? Aq : (z == 1) ? Ak : Av;
    const float* W = (z == 0) ? Wq : (z == 1) ? Wk : Wv;
    const float* bias = (z == 0) ? bq : (z == 1) ? bk : bv;
    const float scale = (z == 0) ? 0.125f : 1.0f;   // fold 1/sqrt(dh) into q

    const int t = threadIdx.x, w = t >> 6, l = t & 63, lr = l & 15, lg = l >> 4;
    const int wr = (w >> 1) * 64, wc = (w & 1) * 64;

    const int srow = t >> 3;             // 0..31 (row within 32-row group)
    const int sblk = t & 7;              // 8-float k-chunk
    char* AsB = (char*)As; char* BsB = (char*)Bs;

    const float* Abase = A + (size_t)(bm + srow)*1024 + sblk*8;
    const float* Wbase = W + (size_t)(bn + srow)*1024 + sblk*8;

    float4 av[8], wv4[8];
    #pragma unroll
    for (int j = 0; j < 4; j++) {                    // prologue: tile 0 loads
        av[2*j]    = ((const float4*)(Abase + (size_t)(32*j)*1024))[0];
        av[2*j+1]  = ((const float4*)(Abase + (size_t)(32*j)*1024))[1];
        wv4[2*j]   = ((const float4*)(Wbase + (size_t)(32*j)*1024))[0];
        wv4[2*j+1] = ((const float4*)(Wbase + (size_t)(32*j)*1024))[1];
    }

    f32x4 acc[4][4] = {};
    for (int k0 = 0; k0 < 1024; k0 += 64) {
        __syncthreads();                 // prev tile's MFMA reads done
        #pragma unroll
        for (int j = 0; j < 4; j++) {    // cvt + swizzled ds_write (consumes regs)
            const int row = 32*j + srow;
            const int byte = row*128 + ((sblk ^ (row & 7)) << 4);
            uint4 ua, uw;
            ua.x = cvtpk(av[2*j].x,   av[2*j].y);   ua.y = cvtpk(av[2*j].z,   av[2*j].w);
            ua.z = cvtpk(av[2*j+1].x, av[2*j+1].y); ua.w = cvtpk(av[2*j+1].z, av[2*j+1].w);
            uw.x = cvtpk(wv4[2*j].x,   wv4[2*j].y);   uw.y = cvtpk(wv4[2*j].z,   wv4[2*j].w);
            uw.z = cvtpk(wv4[2*j+1].x, wv4[2*j+1].y); uw.w = cvtpk(wv4[2*j+1].z, wv4[2*j+1].w);
            *(uint4*)(AsB + byte) = ua;
            *(uint4*)(BsB + byte) = uw;
        }
        if (k0 < 960) {                  // issue tile t+1 loads (wait at next cvt)
            #pragma unroll
            for (int j = 0; j < 4; j++) {
                const float* ap = Abase + (size_t)(32*j)*1024 + k0 + 64;
                const float* wp = Wbase + (size_t)(32*j)*1024 + k0 + 64;
                av[2*j]    = ((const float4*)ap)[0];
                av[2*j+1]  = ((const float4*)ap)[1];
                wv4[2*j]   = ((const float4*)wp)[0];
                wv4[2*j+1] = ((const float4*)wp)[1];
            }
        }
        __syncthreads();                 // tile t LDS visible
        #pragma unroll
        for (int s = 0; s < 2; s++) {
            short8 af[4], bf4[4];
            #pragma unroll
            for (int i = 0; i < 4; i++) {
                const int row = wr + 16*i + lr;
                af[i] = *(const short8*)(AsB + row*128 + (((4*s + lg) ^ (row & 7)) << 4));
            }
            #pragma unroll
            for (int j = 0; j < 4; j++) {
                const int row = wc + 16*j + lr;
                bf4[j] = *(const short8*)(BsB + row*128 + (((4*s + lg) ^ (row & 7)) << 4));
            }
            #pragma unroll
            for (int i = 0; i < 4; i++)
                #pragma unroll
                for (int j = 0; j < 4; j++)
                    acc[i][j] = __builtin_amdgcn_mfma_f32_16x16x32_bf16(af[i], bf4[j], acc[i][j], 0, 0, 0);
        }
    }

    if (z < 2) {
        unsigned short* outp = (z == 0) ? qw : kw;
        #pragma unroll
        for (int j = 0; j < 4; j++) {
            const int n = bn + wc + 16*j + lr;
            const float bvx = bias[n];
            const int h = n >> 6, dh = n & 63;
            #pragma unroll
            for (int i = 0; i < 4; i++)
                #pragma unroll
                for (int r = 0; r < 4; r++) {
                    const int m = bm + wr + 16*i + 4*lg + r;   // D row = 4*(l>>4)+reg
                    const int bb = m >> 9, s = m & 511;
                    outp[(((size_t)(bb*H_ + h))*S_ + s)*DH_ + dh] = f2bf((acc[i][j][r] + bvx) * scale);
                }
        }
    } else {
        // V: write transposed [bh][dh][s]; r -> consecutive s -> ushort4
        #pragma unroll
        for (int j = 0; j < 4; j++) {
            const int n = bn + wc + 16*j + lr;
            const float bvx = bias[n];
            const int h = n >> 6, dh = n & 63;
            #pragma unroll
            for (int i = 0; i < 4; i++) {
                const int m0 = bm + wr + 16*i + 4*lg;          // s0 = m0&511 (4-aligned)
                const int bb = m0 >> 9, s0 = m0 & 511;
                ushort4 u;
                u.x = f2bf(acc[i][j][0] + bvx); u.y = f2bf(acc[i][j][1] + bvx);
                u.z = f2bf(acc[i][j][2] + bvx); u.w = f2bf(acc[i][j][3] + bvx);
                *(ushort4*)&vtw[(((size_t)(bb*H_ + h))*DH_ + dh)*S_ + s0] = u;
            }
        }
    }
}

// ---------------------------------------------------------------------------
// E[b][q][k] = c_t*time_attn + c_r*rel_attn  (head-independent), bf16 out.
// R1 = sigmoid(gf-cf)+gf is constant along k -> cancels in softmax.
// ---------------------------------------------------------------------------
__global__ __launch_bounds__(256) void e_kernel(
    const float* __restrict__ rel, const float* __restrict__ tsp,
    const float* __restrict__ pl1, const float* __restrict__ pl2,
    unsigned short* __restrict__ E)
{
    const int t = threadIdx.x, w = t >> 6, l = t & 63;
    const int ridx = blockIdx.x * 4 + w;        // b*S + q
    const int q = ridx & (S_ - 1);
    const float l1 = *pl1, l2 = *pl2;
    const float c_t = (1.f - l1) * l2, c_r = l1;
    const float* tr = tsp + (size_t)ridx * S_;
    const float* rr = rel + (size_t)ridx * S_;

    float tv[8], rv[8]; float st = 0.f, sr = 0.f;
    #pragma unroll
    for (int j = 0; j < 8; j++) {
        const int k = l + 64*j;
        const float rvv = rr[k];
        rv[j] = (rvv != 0.f) ? __expf(rvv) : 0.f;   // exp(-10000)==0 exactly
        sr += rv[j];
        float tvv = 0.f;
        if (k <= q) tvv = __expf(__expf(-fabsf(tr[k])));
        tv[j] = tvv; st += tvv;
    }
    #pragma unroll
    for (int m = 32; m; m >>= 1) { st += __shfl_xor(st, m); sr += __shfl_xor(sr, m); }
    const float ti   = c_t / st;
    const float riv  = (sr > 0.f) ? c_r / sr : 0.f;
    const float runi = (sr > 0.f) ? 0.f : c_r / (float)S_;

    unsigned short* Er = E + (size_t)ridx * S_;
    #pragma unroll
    for (int j = 0; j < 8; j++) {
        const int k = l + 64*j;
        Er[k] = f2bf(tv[j]*ti + rv[j]*riv + runi);
    }
}

// ---------------------------------------------------------------------------
// Fused attention (unchanged from R6). 1D grid 1024; XCD-locality: bid&7 == b.
// prob/out stored NONTEMPORAL to keep K/V/E L2-resident.
// ---------------------------------------------------------------------------
__global__ __launch_bounds__(256) void attn_mfma(
    const unsigned short* __restrict__ qw, const unsigned short* __restrict__ kw,
    const unsigned short* __restrict__ vtw, const unsigned short* __restrict__ E,
    const float* __restrict__ pl1, const float* __restrict__ pl2,
    float* __restrict__ out, float* __restrict__ prob)
{
    __shared__ unsigned short Ps[2][64][72];

    const int t = threadIdx.x, w = t >> 6, l = t & 63, lr = l & 15, lg = l >> 4;
    const int bid = blockIdx.x;
    const int j   = bid >> 3;
    const int bh  = (bid & 7) * 16 + (j & 15);     // b = bid&7, h = j&15
    const int b   = bh >> 4, h = bh & 15;
    const int q0  = (j >> 4) * 64;
    const float l1 = *pl1, l2 = *pl2;
    const float c_p = (1.f - l1) * (1.f - l2);
    const unsigned short* qp = qw + (size_t)bh * (S_ * DH_);
    const unsigned short* kp = kw + (size_t)bh * (S_ * DH_);
    const unsigned short* vt = vtw + (size_t)bh * (DH_ * S_);

    short8 qa[2];
    #pragma unroll
    for (int s = 0; s < 2; s++)
        qa[s] = *(const short8*)&qp[(size_t)(q0 + 16*w + lr)*DH_ + 32*s + 8*lg];

    const int qrb = q0 + 16*w + 4*lg;    // +i = absolute q row for acc elem i

    // ---- pass 1: QK^T, pack scores (bf16 pairs) with causal mask ----
    unsigned int scp[8][4][2];
    #pragma unroll
    for (int ch = 0; ch < 8; ch++) {
        f32x4 a4[4] = {};
        #pragma unroll
        for (int s = 0; s < 2; s++)
            #pragma unroll
            for (int g = 0; g < 4; g++) {
                const short8 kb = *(const short8*)&kp[(size_t)(ch*64 + 16*g + lr)*DH_ + 32*s + 8*lg];
                a4[g] = __builtin_amdgcn_mfma_f32_16x16x32_bf16(qa[s], kb, a4[g], 0, 0, 0);
            }
        #pragma unroll
        for (int g = 0; g < 4; g++) {
            const int k = 64*ch + 16*g + lr;
            const float v0 = (k <= qrb + 0) ? a4[g][0] : -1e30f;
            const float v1 = (k <= qrb + 1) ? a4[g][1] : -1e30f;
            const float v2 = (k <= qrb + 2) ? a4[g][2] : -1e30f;
            const float v3 = (k <= qrb + 3) ? a4[g][3] : -1e30f;
            scp[ch][g][0] = ((unsigned)f2bf(v1) << 16) | f2bf(v0);
            scp[ch][g][1] = ((unsigned)f2bf(v3) << 16) | f2bf(v2);
        }
    }

    // ---- softmax over packed scores ----
    float mx[4] = {-1e30f, -1e30f, -1e30f, -1e30f};
    #pragma unroll
    for (int ch = 0; ch < 8; ch++)
        #pragma unroll
        for (int g = 0; g < 4; g++) {
            const unsigned u0 = scp[ch][g][0], u1 = scp[ch][g][1];
            mx[0] = fmaxf(mx[0], __uint_as_float(u0 << 16));
            mx[1] = fmaxf(mx[1], __uint_as_float(u0 & 0xffff0000u));
            mx[2] = fmaxf(mx[2], __uint_as_float(u1 << 16));
            mx[3] = fmaxf(mx[3], __uint_as_float(u1 & 0xffff0000u));
        }
    #pragma unroll
    for (int i = 0; i < 4; i++)
        #pragma unroll
        for (int m = 8; m; m >>= 1) mx[i] = fmaxf(mx[i], __shfl_xor(mx[i], m));

    float sm[4] = {0.f, 0.f, 0.f, 0.f};
    #pragma unroll
    for (int ch = 0; ch < 8; ch++)
        #pragma unroll
        for (int g = 0; g < 4; g++) {
            const unsigned u0 = scp[ch][g][0], u1 = scp[ch][g][1];
            const float e0 = __expf(__uint_as_float(u0 << 16)          - mx[0]);
            const float e1 = __expf(__uint_as_float(u0 & 0xffff0000u) - mx[1]);
            const float e2 = __expf(__uint_as_float(u1 << 16)          - mx[2]);
            const float e3 = __expf(__uint_as_float(u1 & 0xffff0000u) - mx[3]);
            sm[0] += e0; sm[1] += e1; sm[2] += e2; sm[3] += e3;
            scp[ch][g][0] = ((unsigned)f2bf(e1) << 16) | f2bf(e0);
            scp[ch][g][1] = ((unsigned)f2bf(e3) << 16) | f2bf(e2);
        }
    #pragma unroll
    for (int i = 0; i < 4; i++)
        #pragma unroll
        for (int m = 8; m; m >>= 1) sm[i] += __shfl_xor(sm[i], m);
    float pinv[4];
    #pragma unroll
    for (int i = 0; i < 4; i++) pinv[i] = c_p / sm[i];

    // ---- pass 2: fin -> Ps (dbuf) + nontemporal prob stores; PV MFMA ----
    f32x4 pv[4] = {};
    const unsigned short* Eb = E + ((size_t)b * S_ + qrb) * S_;
    float* pr = prob + ((size_t)bh * S_ + qrb) * S_;
    const int prow = 16*w + 4*lg;

    #pragma unroll
    for (int ch = 0; ch < 8; ch++) {
        const int p = ch & 1;
        #pragma unroll
        for (int g = 0; g < 4; g++) {
            const int kc = 16*g + lr;
            const unsigned u0 = scp[ch][g][0], u1 = scp[ch][g][1];
            const size_t eb = (size_t)(64*ch + kc);
            const float f0 = __uint_as_float(u0 << 16)          * pinv[0] + bf2f(Eb[eb]);
            const float f1 = __uint_as_float(u0 & 0xffff0000u) * pinv[1] + bf2f(Eb[eb + 512]);
            const float f2 = __uint_as_float(u1 << 16)          * pinv[2] + bf2f(Eb[eb + 1024]);
            const float f3 = __uint_as_float(u1 & 0xffff0000u) * pinv[3] + bf2f(Eb[eb + 1536]);
            Ps[p][prow + 0][kc] = f2bf(f0);
            Ps[p][prow + 1][kc] = f2bf(f1);
            Ps[p][prow + 2][kc] = f2bf(f2);
            Ps[p][prow + 3][kc] = f2bf(f3);
            __builtin_nontemporal_store(f0, &pr[eb]);
            __builtin_nontemporal_store(f1, &pr[eb + 512]);
            __builtin_nontemporal_store(f2, &pr[eb + 1024]);
            __builtin_nontemporal_store(f3, &pr[eb + 1536]);
        }
        __syncthreads();
        #pragma unroll
        for (int s = 0; s < 2; s++) {
            const short8 pa = *(const short8*)&Ps[p][16*w + lr][32*s + 8*lg];
            #pragma unroll
            for (int g = 0; g < 4; g++) {
                const short8 vb = *(const short8*)&vt[(size_t)(16*g + lr)*S_ + 64*ch + 32*s + 8*lg];
                pv[g] = __builtin_amdgcn_mfma_f32_16x16x32_bf16(pa, vb, pv[g], 0, 0, 0);
            }
        }
    }

    #pragma unroll
    for (int g = 0; g < 4; g++)
        #pragma unroll
        for (int i = 0; i < 4; i++)
            __builtin_nontemporal_store(pv[g][i],
                &out[((size_t)(b*S_ + qrb + i))*D_ + h*DH_ + 16*g + lr]);
}

// ---------------------------------------------------------------------------
extern "C" void kernel_launch(void* const* d_in, const int* in_sizes, int n_in,
                              void* d_out, int out_size, void* d_ws, size_t ws_size,
                              hipStream_t stream)
{
    const float* query = (const float*)d_in[0];
    const float* key   = (const float*)d_in[1];
    const float* value = (const float*)d_in[2];
    const float* rel   = (const float*)d_in[3];
    const float* tsp   = (const float*)d_in[4];
    const float* l1    = (const float*)d_in[5];
    const float* l2    = (const float*)d_in[6];
    // d_in[7]=mask (causal, recomputed), d_in[8]=encode_pos (unused)
    const float* Wq = (const float*)d_in[9];
    const float* bq = (const float*)d_in[10];
    const float* Wk = (const float*)d_in[11];
    const float* bk = (const float*)d_in[12];
    const float* Wv = (const float*)d_in[13];
    const float* bv = (const float*)d_in[14];
    // Wc/bc/Wg/bg (15..18): R1 constant along softmax axis -> cancels

    float* out  = (float*)d_out;
    float* prob = (float*)d_out + (size_t)B_ * S_ * D_;

    const size_t headN = (size_t)B_ * H_ * S_ * DH_;       // 4,194,304
    unsigned short* qw  = (unsigned short*)d_ws;
    unsigned short* kw  = qw + headN;
    unsigned short* vtw = kw + headN;
    unsigned short* Ew  = vtw + headN;                     // B*S*S bf16 = 4.2 MB

    qkv_gemm<<<768, 256, 0, stream>>>(query, key, value, Wq, Wk, Wv,
                                      bq, bk, bv, qw, kw, vtw);

    e_kernel<<<(B_ * S_) / 4, 256, 0, stream>>>(rel, tsp, l1, l2, Ew);

    attn_mfma<<<1024, 256, 0, stream>>>(qw, kw, vtw, Ew, l1, l2, out, prob);
}

// Round 8
// 126.420 us; speedup vs baseline: 7.4557x; 1.0251x over previous
//
#include <hip/hip_runtime.h>
#include <math.h>

typedef __attribute__((ext_vector_type(8))) short short8;
typedef __attribute__((ext_vector_type(4))) float f32x4;

#define B_  8
#define S_  512
#define D_  1024
#define H_  16
#define DH_ 64

__device__ __forceinline__ unsigned short f2bf(float f) {
    unsigned int u = __float_as_uint(f);
    u += 0x7FFFu + ((u >> 16) & 1u);      // round-to-nearest-even
    return (unsigned short)(u >> 16);
}
__device__ __forceinline__ float bf2f(unsigned short u) {
    return __uint_as_float(((unsigned int)u) << 16);
}
// 2x f32 -> packed bf16 (RNE), lo in low 16 bits
__device__ __forceinline__ unsigned cvtpk(float lo, float hi) {
    unsigned r;
    asm("v_cvt_pk_bf16_f32 %0, %1, %2" : "=v"(r) : "v"(lo), "v"(hi));
    return r;
}

// ---------------------------------------------------------------------------
// Fused QKV projection GEMM, T14 pipeline with RAW barriers (no vmcnt drain):
// __syncthreads would emit s_waitcnt vmcnt(0) before s_barrier and kill the
// prefetch; raw s_barrier + explicit lgkmcnt(0) keeps tile t+1's global loads
// in flight across both barriers — their wait lands at tile t+1's cvt,
// hidden under ds_write + 32 MFMAs.
// z==0/1: q/k in head layout [bh][s][dh] (0.125 folded into q).
// z==2:   V directly transposed [bh][dh][s] (ushort4 stores).
// 1D grid 768, XCD-bijective swizzle (768%8==0).
// ---------------------------------------------------------------------------
__global__ __launch_bounds__(256, 3) void qkv_gemm(
    const float* __restrict__ Aq, const float* __restrict__ Ak, const float* __restrict__ Av,
    const float* __restrict__ Wq, const float* __restrict__ Wk, const float* __restrict__ Wv,
    const float* __restrict__ bq, const float* __restrict__ bk, const float* __restrict__ bv,
    unsigned short* __restrict__ qw, unsigned short* __restrict__ kw,
    unsigned short* __restrict__ vtw)
{
    __shared__ unsigned short As[128][64];   // 16 KB, content XOR-swizzled
    __shared__ unsigned short Bs[128][64];

    const int bid = blockIdx.x;
    const int wid = (bid & 7) * 96 + (bid >> 3);
    const int z   = wid >> 8;            // tensor
    const int rem = wid & 255;
    const int bm  = (rem >> 3) * 128;    // m-block
    const int bn  = (rem & 7) * 128;     // n-block

    const float* A = (z == 0) ? Aq : (z == 1) ? Ak : Av;
    const float* W = (z == 0) ? Wq : (z == 1) ? Wk : Wv;
    const float* bias = (z == 0) ? bq : (z == 1) ? bk : bv;
    const float scale = (z == 0) ? 0.125f : 1.0f;   // fold 1/sqrt(dh) into q

    const int t = threadIdx.x, w = t >> 6, l = t & 63, lr = l & 15, lg = l >> 4;
    const int wr = (w >> 1) * 64, wc = (w & 1) * 64;

    const int srow = t >> 3;             // 0..31 (row within 32-row group)
    const int sblk = t & 7;              // 8-float k-chunk
    char* AsB = (char*)As; char* BsB = (char*)Bs;

    const float* Abase = A + (size_t)(bm + srow)*1024 + sblk*8;
    const float* Wbase = W + (size_t)(bn + srow)*1024 + sblk*8;

    float4 av[8], wv4[8];
    #pragma unroll
    for (int j = 0; j < 4; j++) {                    // prologue: tile 0 loads
        av[2*j]    = ((const float4*)(Abase + (size_t)(32*j)*1024))[0];
        av[2*j+1]  = ((const float4*)(Abase + (size_t)(32*j)*1024))[1];
        wv4[2*j]   = ((const float4*)(Wbase + (size_t)(32*j)*1024))[0];
        wv4[2*j+1] = ((const float4*)(Wbase + (size_t)(32*j)*1024))[1];
    }

    f32x4 acc[4][4] = {};
    for (int k0 = 0; k0 < 1024; k0 += 64) {
        __builtin_amdgcn_s_barrier();    // (A) all waves done reading prev LDS tile
        #pragma unroll
        for (int j = 0; j < 4; j++) {    // cvt (vmcnt waits here) + swizzled ds_write
            const int row = 32*j + srow;
            const int byte = row*128 + ((sblk ^ (row & 7)) << 4);
            uint4 ua, uw;
            ua.x = cvtpk(av[2*j].x,   av[2*j].y);   ua.y = cvtpk(av[2*j].z,   av[2*j].w);
            ua.z = cvtpk(av[2*j+1].x, av[2*j+1].y); ua.w = cvtpk(av[2*j+1].z, av[2*j+1].w);
            uw.x = cvtpk(wv4[2*j].x,   wv4[2*j].y);   uw.y = cvtpk(wv4[2*j].z,   wv4[2*j].w);
            uw.z = cvtpk(wv4[2*j+1].x, wv4[2*j+1].y); uw.w = cvtpk(wv4[2*j+1].z, wv4[2*j+1].w);
            *(uint4*)(AsB + byte) = ua;
            *(uint4*)(BsB + byte) = uw;
        }
        if (k0 < 960) {                  // issue tile t+1 loads; stay in flight
            #pragma unroll
            for (int j = 0; j < 4; j++) {
                const float* ap = Abase + (size_t)(32*j)*1024 + k0 + 64;
                const float* wp = Wbase + (size_t)(32*j)*1024 + k0 + 64;
                av[2*j]    = ((const float4*)ap)[0];
                av[2*j+1]  = ((const float4*)ap)[1];
                wv4[2*j]   = ((const float4*)wp)[0];
                wv4[2*j+1] = ((const float4*)wp)[1];
            }
        }
        asm volatile("s_waitcnt lgkmcnt(0)" ::: "memory");  // ds_writes visible
        __builtin_amdgcn_s_barrier();    // (B) tile t readable by all waves
        __builtin_amdgcn_sched_barrier(0);                  // rule #18 fence
        #pragma unroll
        for (int s = 0; s < 2; s++) {
            short8 af[4], bf4[4];
            #pragma unroll
            for (int i = 0; i < 4; i++) {
                const int row = wr + 16*i + lr;
                af[i] = *(const short8*)(AsB + row*128 + (((4*s + lg) ^ (row & 7)) << 4));
            }
            #pragma unroll
            for (int j = 0; j < 4; j++) {
                const int row = wc + 16*j + lr;
                bf4[j] = *(const short8*)(BsB + row*128 + (((4*s + lg) ^ (row & 7)) << 4));
            }
            #pragma unroll
            for (int i = 0; i < 4; i++)
                #pragma unroll
                for (int j = 0; j < 4; j++)
                    acc[i][j] = __builtin_amdgcn_mfma_f32_16x16x32_bf16(af[i], bf4[j], acc[i][j], 0, 0, 0);
        }
    }

    if (z < 2) {
        unsigned short* outp = (z == 0) ? qw : kw;
        #pragma unroll
        for (int j = 0; j < 4; j++) {
            const int n = bn + wc + 16*j + lr;
            const float bvx = bias[n];
            const int h = n >> 6, dh = n & 63;
            #pragma unroll
            for (int i = 0; i < 4; i++)
                #pragma unroll
                for (int r = 0; r < 4; r++) {
                    const int m = bm + wr + 16*i + 4*lg + r;   // D row = 4*(l>>4)+reg
                    const int bb = m >> 9, s = m & 511;
                    outp[(((size_t)(bb*H_ + h))*S_ + s)*DH_ + dh] = f2bf((acc[i][j][r] + bvx) * scale);
                }
        }
    } else {
        // V: write transposed [bh][dh][s]; r -> consecutive s -> ushort4
        #pragma unroll
        for (int j = 0; j < 4; j++) {
            const int n = bn + wc + 16*j + lr;
            const float bvx = bias[n];
            const int h = n >> 6, dh = n & 63;
            #pragma unroll
            for (int i = 0; i < 4; i++) {
                const int m0 = bm + wr + 16*i + 4*lg;          // s0 = m0&511 (4-aligned)
                const int bb = m0 >> 9, s0 = m0 & 511;
                ushort4 u;
                u.x = f2bf(acc[i][j][0] + bvx); u.y = f2bf(acc[i][j][1] + bvx);
                u.z = f2bf(acc[i][j][2] + bvx); u.w = f2bf(acc[i][j][3] + bvx);
                *(ushort4*)&vtw[(((size_t)(bb*H_ + h))*DH_ + dh)*S_ + s0] = u;
            }
        }
    }
}

// ---------------------------------------------------------------------------
// E[b][q][k] = c_t*time_attn + c_r*rel_attn  (head-independent), bf16 out.
// R1 = sigmoid(gf-cf)+gf is constant along k -> cancels in softmax.
// ---------------------------------------------------------------------------
__global__ __launch_bounds__(256) void e_kernel(
    const float* __restrict__ rel, const float* __restrict__ tsp,
    const float* __restrict__ pl1, const float* __restrict__ pl2,
    unsigned short* __restrict__ E)
{
    const int t = threadIdx.x, w = t >> 6, l = t & 63;
    const int ridx = blockIdx.x * 4 + w;        // b*S + q
    const int q = ridx & (S_ - 1);
    const float l1 = *pl1, l2 = *pl2;
    const float c_t = (1.f - l1) * l2, c_r = l1;
    const float* tr = tsp + (size_t)ridx * S_;
    const float* rr = rel + (size_t)ridx * S_;

    float tv[8], rv[8]; float st = 0.f, sr = 0.f;
    #pragma unroll
    for (int j = 0; j < 8; j++) {
        const int k = l + 64*j;
        const float rvv = rr[k];
        rv[j] = (rvv != 0.f) ? __expf(rvv) : 0.f;   // exp(-10000)==0 exactly
        sr += rv[j];
        float tvv = 0.f;
        if (k <= q) tvv = __expf(__expf(-fabsf(tr[k])));
        tv[j] = tvv; st += tvv;
    }
    #pragma unroll
    for (int m = 32; m; m >>= 1) { st += __shfl_xor(st, m); sr += __shfl_xor(sr, m); }
    const float ti   = c_t / st;
    const float riv  = (sr > 0.f) ? c_r / sr : 0.f;
    const float runi = (sr > 0.f) ? 0.f : c_r / (float)S_;

    unsigned short* Er = E + (size_t)ridx * S_;
    #pragma unroll
    for (int j = 0; j < 8; j++) {
        const int k = l + 64*j;
        Er[k] = f2bf(tv[j]*ti + rv[j]*riv + runi);
    }
}

// ---------------------------------------------------------------------------
// Fused attention (unchanged). 1D grid 1024; XCD-locality: bid&7 == b.
// prob/out stored NONTEMPORAL to keep K/V/E L2-resident.
// ---------------------------------------------------------------------------
__global__ __launch_bounds__(256) void attn_mfma(
    const unsigned short* __restrict__ qw, const unsigned short* __restrict__ kw,
    const unsigned short* __restrict__ vtw, const unsigned short* __restrict__ E,
    const float* __restrict__ pl1, const float* __restrict__ pl2,
    float* __restrict__ out, float* __restrict__ prob)
{
    __shared__ unsigned short Ps[2][64][72];

    const int t = threadIdx.x, w = t >> 6, l = t & 63, lr = l & 15, lg = l >> 4;
    const int bid = blockIdx.x;
    const int j   = bid >> 3;
    const int bh  = (bid & 7) * 16 + (j & 15);     // b = bid&7, h = j&15
    const int b   = bh >> 4, h = bh & 15;
    const int q0  = (j >> 4) * 64;
    const float l1 = *pl1, l2 = *pl2;
    const float c_p = (1.f - l1) * (1.f - l2);
    const unsigned short* qp = qw + (size_t)bh * (S_ * DH_);
    const unsigned short* kp = kw + (size_t)bh * (S_ * DH_);
    const unsigned short* vt = vtw + (size_t)bh * (DH_ * S_);

    short8 qa[2];
    #pragma unroll
    for (int s = 0; s < 2; s++)
        qa[s] = *(const short8*)&qp[(size_t)(q0 + 16*w + lr)*DH_ + 32*s + 8*lg];

    const int qrb = q0 + 16*w + 4*lg;    // +i = absolute q row for acc elem i

    // ---- pass 1: QK^T, pack scores (bf16 pairs) with causal mask ----
    unsigned int scp[8][4][2];
    #pragma unroll
    for (int ch = 0; ch < 8; ch++) {
        f32x4 a4[4] = {};
        #pragma unroll
        for (int s = 0; s < 2; s++)
            #pragma unroll
            for (int g = 0; g < 4; g++) {
                const short8 kb = *(const short8*)&kp[(size_t)(ch*64 + 16*g + lr)*DH_ + 32*s + 8*lg];
                a4[g] = __builtin_amdgcn_mfma_f32_16x16x32_bf16(qa[s], kb, a4[g], 0, 0, 0);
            }
        #pragma unroll
        for (int g = 0; g < 4; g++) {
            const int k = 64*ch + 16*g + lr;
            const float v0 = (k <= qrb + 0) ? a4[g][0] : -1e30f;
            const float v1 = (k <= qrb + 1) ? a4[g][1] : -1e30f;
            const float v2 = (k <= qrb + 2) ? a4[g][2] : -1e30f;
            const float v3 = (k <= qrb + 3) ? a4[g][3] : -1e30f;
            scp[ch][g][0] = ((unsigned)f2bf(v1) << 16) | f2bf(v0);
            scp[ch][g][1] = ((unsigned)f2bf(v3) << 16) | f2bf(v2);
        }
    }

    // ---- softmax over packed scores ----
    float mx[4] = {-1e30f, -1e30f, -1e30f, -1e30f};
    #pragma unroll
    for (int ch = 0; ch < 8; ch++)
        #pragma unroll
        for (int g = 0; g < 4; g++) {
            const unsigned u0 = scp[ch][g][0], u1 = scp[ch][g][1];
            mx[0] = fmaxf(mx[0], __uint_as_float(u0 << 16));
            mx[1] = fmaxf(mx[1], __uint_as_float(u0 & 0xffff0000u));
            mx[2] = fmaxf(mx[2], __uint_as_float(u1 << 16));
            mx[3] = fmaxf(mx[3], __uint_as_float(u1 & 0xffff0000u));
        }
    #pragma unroll
    for (int i = 0; i < 4; i++)
        #pragma unroll
        for (int m = 8; m; m >>= 1) mx[i] = fmaxf(mx[i], __shfl_xor(mx[i], m));

    float sm[4] = {0.f, 0.f, 0.f, 0.f};
    #pragma unroll
    for (int ch = 0; ch < 8; ch++)
        #pragma unroll
        for (int g = 0; g < 4; g++) {
            const unsigned u0 = scp[ch][g][0], u1 = scp[ch][g][1];
            const float e0 = __expf(__uint_as_float(u0 << 16)          - mx[0]);
            const float e1 = __expf(__uint_as_float(u0 & 0xffff0000u) - mx[1]);
            const float e2 = __expf(__uint_as_float(u1 << 16)          - mx[2]);
            const float e3 = __expf(__uint_as_float(u1 & 0xffff0000u) - mx[3]);
            sm[0] += e0; sm[1] += e1; sm[2] += e2; sm[3] += e3;
            scp[ch][g][0] = ((unsigned)f2bf(e1) << 16) | f2bf(e0);
            scp[ch][g][1] = ((unsigned)f2bf(e3) << 16) | f2bf(e2);
        }
    #pragma unroll
    for (int i = 0; i < 4; i++)
        #pragma unroll
        for (int m = 8; m; m >>= 1) sm[i] += __shfl_xor(sm[i], m);
    float pinv[4];
    #pragma unroll
    for (int i = 0; i < 4; i++) pinv[i] = c_p / sm[i];

    // ---- pass 2: fin -> Ps (dbuf) + nontemporal prob stores; PV MFMA ----
    f32x4 pv[4] = {};
    const unsigned short* Eb = E + ((size_t)b * S_ + qrb) * S_;
    float* pr = prob + ((size_t)bh * S_ + qrb) * S_;
    const int prow = 16*w + 4*lg;

    #pragma unroll
    for (int ch = 0; ch < 8; ch++) {
        const int p = ch & 1;
        #pragma unroll
        for (int g = 0; g < 4; g++) {
            const int kc = 16*g + lr;
            const unsigned u0 = scp[ch][g][0], u1 = scp[ch][g][1];
            const size_t eb = (size_t)(64*ch + kc);
            const float f0 = __uint_as_float(u0 << 16)          * pinv[0] + bf2f(Eb[eb]);
            const float f1 = __uint_as_float(u0 & 0xffff0000u) * pinv[1] + bf2f(Eb[eb + 512]);
            const float f2 = __uint_as_float(u1 << 16)          * pinv[2] + bf2f(Eb[eb + 1024]);
            const float f3 = __uint_as_float(u1 & 0xffff0000u) * pinv[3] + bf2f(Eb[eb + 1536]);
            Ps[p][prow + 0][kc] = f2bf(f0);
            Ps[p][prow + 1][kc] = f2bf(f1);
            Ps[p][prow + 2][kc] = f2bf(f2);
            Ps[p][prow + 3][kc] = f2bf(f3);
            __builtin_nontemporal_store(f0, &pr[eb]);
            __builtin_nontemporal_store(f1, &pr[eb + 512]);
            __builtin_nontemporal_store(f2, &pr[eb + 1024]);
            __builtin_nontemporal_store(f3, &pr[eb + 1536]);
        }
        __syncthreads();
        #pragma unroll
        for (int s = 0; s < 2; s++) {
            const short8 pa = *(const short8*)&Ps[p][16*w + lr][32*s + 8*lg];
            #pragma unroll
            for (int g = 0; g < 4; g++) {
                const short8 vb = *(const short8*)&vt[(size_t)(16*g + lr)*S_ + 64*ch + 32*s + 8*lg];
                pv[g] = __builtin_amdgcn_mfma_f32_16x16x32_bf16(pa, vb, pv[g], 0, 0, 0);
            }
        }
    }

    #pragma unroll
    for (int g = 0; g < 4; g++)
        #pragma unroll
        for (int i = 0; i < 4; i++)
            __builtin_nontemporal_store(pv[g][i],
                &out[((size_t)(b*S_ + qrb + i))*D_ + h*DH_ + 16*g + lr]);
}

// ---------------------------------------------------------------------------
extern "C" void kernel_launch(void* const* d_in, const int* in_sizes, int n_in,
                              void* d_out, int out_size, void* d_ws, size_t ws_size,
                              hipStream_t stream)
{
    const float* query = (const float*)d_in[0];
    const float* key   = (const float*)d_in[1];
    const float* value = (const float*)d_in[2];
    const float* rel   = (const float*)d_in[3];
    const float* tsp   = (const float*)d_in[4];
    const float* l1    = (const float*)d_in[5];
    const float* l2    = (const float*)d_in[6];
    // d_in[7]=mask (causal, recomputed), d_in[8]=encode_pos (unused)
    const float* Wq = (const float*)d_in[9];
    const float* bq = (const float*)d_in[10];
    const float* Wk = (const float*)d_in[11];
    const float* bk = (const float*)d_in[12];
    const float* Wv = (const float*)d_in[13];
    const float* bv = (const float*)d_in[14];
    // Wc/bc/Wg/bg (15..18): R1 constant along softmax axis -> cancels

    float* out  = (float*)d_out;
    float* prob = (float*)d_out + (size_t)B_ * S_ * D_;

    const size_t headN = (size_t)B_ * H_ * S_ * DH_;       // 4,194,304
    unsigned short* qw  = (unsigned short*)d_ws;
    unsigned short* kw  = qw + headN;
    unsigned short* vtw = kw + headN;
    unsigned short* Ew  = vtw + headN;                     // B*S*S bf16 = 4.2 MB

    qkv_gemm<<<768, 256, 0, stream>>>(query, key, value, Wq, Wk, Wv,
                                      bq, bk, bv, qw, kw, vtw);

    e_kernel<<<(B_ * S_) / 4, 256, 0, stream>>>(rel, tsp, l1, l2, Ew);

    attn_mfma<<<1024, 256, 0, stream>>>(qw, kw, vtw, Ew, l1, l2, out, prob);
}